// Round 5
// baseline (2589.482 us; speedup 1.0000x reference)
//
#include <hip/hip_runtime.h>
#include <hip/hip_bf16.h>
#include <math.h>

#define BATCH 2
#define SEQ   2048
#define DMODEL 768
#define DIN   384
#define DINNER 768
#define DSTATE 16
#define DTRANK 24
#define ROWS  (BATCH*SEQ)   // 4096
#define NCH   64            // time chunks for the scan
#define CLEN  (SEQ/NCH)     // 32 steps per chunk
#define NB    768           // persistent grid: 3 blocks/CU x 256 CUs

using short8  = __attribute__((ext_vector_type(8))) short;
using floatx4 = __attribute__((ext_vector_type(4))) float;

__device__ __forceinline__ ushort f2bf(float f) {
    union { float f; uint u; } v; v.f = f;
    uint r = (v.u + 0x7fffu + ((v.u >> 16) & 1u)) >> 16;
    return (ushort)r;
}
__device__ __forceinline__ float bf2f(ushort h) {
    union { uint u; float f; } v; v.u = ((uint)h) << 16;
    return v.f;
}
__device__ __forceinline__ void async16(const ushort* g, ushort* l) {
    __builtin_amdgcn_global_load_lds(
        (const __attribute__((address_space(1))) void*)g,
        (__attribute__((address_space(3))) void*)l,
        16, 0, 0);
}

// ---------------------------------------------------------------------------
// Shared-memory overlays
// ---------------------------------------------------------------------------
struct GemmSh { ushort lA[128 * 64]; ushort lB[64 * 64]; };          // 24 KB
struct DtSh   { float As[16][68]; float Bs[16][68]; };               // 8.7 KB
struct LnSh   { float ss[4]; float ssq[4]; float m; float rs; };
union MegaSh  { GemmSh g; DtSh d; LnSh l; };

// ---------------------------------------------------------------------------
// Device-scope grid barrier (sense-reversing, generation counter).
// Requires all NB blocks co-resident (guaranteed by __launch_bounds__(256,3)).
// ---------------------------------------------------------------------------
__device__ __forceinline__ void gbar(uint* cnt, uint* gen) {
    __syncthreads();
    if (threadIdx.x == 0) {
        __threadfence();   // writeback own-XCD L2 (prior stores visible device-wide)
        uint g = __hip_atomic_load(gen, __ATOMIC_RELAXED, __HIP_MEMORY_SCOPE_AGENT);
        uint a = __hip_atomic_fetch_add(cnt, 1u, __ATOMIC_ACQ_REL, __HIP_MEMORY_SCOPE_AGENT);
        if (a == NB - 1) {
            __hip_atomic_store(cnt, 0u, __ATOMIC_RELAXED, __HIP_MEMORY_SCOPE_AGENT);
            __hip_atomic_fetch_add(gen, 1u, __ATOMIC_RELEASE, __HIP_MEMORY_SCOPE_AGENT);
        } else {
            while (__hip_atomic_load(gen, __ATOMIC_ACQUIRE, __HIP_MEMORY_SCOPE_AGENT) == g)
                __builtin_amdgcn_s_sleep(2);
        }
        __threadfence();   // invalidate L1/L2 before post-barrier reads
    }
    __syncthreads();
}

// ---------------------------------------------------------------------------
// LayerNorm row (optionally + residual). 256 threads, row of 768.
// ---------------------------------------------------------------------------
template<bool OUT_BF>
__device__ __forceinline__ void ln_row(
    int row, const float* __restrict__ x, const float* __restrict__ res,
    const float* __restrict__ w, const float* __restrict__ b,
    void* __restrict__ out, LnSh& sh)
{
    int tid = threadIdx.x;
    const float* xr = x + (size_t)row * DMODEL;
    const float* rr = res ? res + (size_t)row * DMODEL : nullptr;
    float v[3];
    float s = 0.f, sq = 0.f;
#pragma unroll
    for (int j = 0; j < 3; j++) {
        int i = tid + j * 256;
        float val = xr[i];
        if (rr) val += rr[i];
        v[j] = val; s += val; sq += val * val;
    }
#pragma unroll
    for (int off = 32; off; off >>= 1) {
        s  += __shfl_down(s,  off);
        sq += __shfl_down(sq, off);
    }
    int wid = tid >> 6;
    if ((tid & 63) == 0) { sh.ss[wid] = s; sh.ssq[wid] = sq; }
    __syncthreads();
    if (tid == 0) {
        float S  = sh.ss[0] + sh.ss[1] + sh.ss[2] + sh.ss[3];
        float SQ = sh.ssq[0] + sh.ssq[1] + sh.ssq[2] + sh.ssq[3];
        float m  = S * (1.0f / DMODEL);
        float var = SQ * (1.0f / DMODEL) - m * m;
        sh.m = m;
        sh.rs = rsqrtf(var + 1e-5f);
    }
    __syncthreads();
    float m = sh.m, rs = sh.rs;
#pragma unroll
    for (int j = 0; j < 3; j++) {
        int i = tid + j * 256;
        float r = (v[j] - m) * rs * w[i] + b[i];
        if (OUT_BF) ((ushort*)out)[(size_t)row * DMODEL + i] = f2bf(r);
        else        ((float*)out)[(size_t)row * DMODEL + i] = r;
    }
    __syncthreads();   // protect sh reuse by next row
}

// ---------------------------------------------------------------------------
// bf16 MFMA GEMM tile (m97 staging, BK=64): C[TMxTN] at (m0,n0).
// ---------------------------------------------------------------------------
template<int TM, int TN, bool OUT_BF>
__device__ __forceinline__ void gemm_tile(
    const ushort* __restrict__ A, int lda,
    const ushort* __restrict__ Bt, int ldb,
    const float* __restrict__ bias,
    void* __restrict__ C, int ldc, int N, int K,
    int m0, int n0, GemmSh& sh)
{
    constexpr int WM = TM / 2, WN = TN / 2;
    constexpr int MT = WM / 16, NT = WN / 16;
    constexpr int AI = TM / 32, BI = TN / 32;   // staging instrs per wave
    const int tid = threadIdx.x;
    const int wave = tid >> 6, lane = tid & 63;
    const int wm = wave >> 1, wn = wave & 1;
    const int quad = lane >> 4, l16 = lane & 15;
    const int lrow = lane >> 3, lcol = (lane & 7) * 8;   // 8 rows x 64 shorts / KB

    floatx4 acc[MT][NT];
#pragma unroll
    for (int i = 0; i < MT; i++)
#pragma unroll
        for (int j = 0; j < NT; j++)
            acc[i][j] = (floatx4){0.f, 0.f, 0.f, 0.f};

    for (int k0 = 0; k0 < K; k0 += 64) {
#pragma unroll
        for (int i = 0; i < AI; i++) {
            int rb = (wave * AI + i) * 8;
            async16(A + (size_t)(m0 + rb + lrow) * lda + k0 + lcol, &sh.lA[rb * 64]);
        }
#pragma unroll
        for (int i = 0; i < BI; i++) {
            int rb = (wave * BI + i) * 8;
            async16(Bt + (size_t)(n0 + rb + lrow) * ldb + k0 + lcol, &sh.lB[rb * 64]);
        }
        __syncthreads();
#pragma unroll
        for (int ks = 0; ks < 2; ks++) {
            short8 af[MT], bf[NT];
#pragma unroll
            for (int i = 0; i < MT; i++)
                af[i] = *(const short8*)&sh.lA[(wm * WM + i * 16 + l16) * 64 + ks * 32 + quad * 8];
#pragma unroll
            for (int j = 0; j < NT; j++)
                bf[j] = *(const short8*)&sh.lB[(wn * WN + j * 16 + l16) * 64 + ks * 32 + quad * 8];
#pragma unroll
            for (int i = 0; i < MT; i++)
#pragma unroll
                for (int j = 0; j < NT; j++)
                    acc[i][j] = __builtin_amdgcn_mfma_f32_16x16x32_bf16(af[i], bf[j], acc[i][j], 0, 0, 0);
        }
        __syncthreads();
    }
#pragma unroll
    for (int i = 0; i < MT; i++) {
#pragma unroll
        for (int j = 0; j < NT; j++) {
            int row = m0 + wm * WM + i * 16 + quad * 4;
            int col = n0 + wn * WN + j * 16 + l16;
            if (col < N) {
                float bv = bias ? bias[col] : 0.f;
#pragma unroll
                for (int r = 0; r < 4; r++) {
                    float v = acc[i][j][r] + bv;
                    if (OUT_BF) ((ushort*)C)[(size_t)(row + r) * ldc + col] = f2bf(v);
                    else        ((float*)C)[(size_t)(row + r) * ldc + col] = v;
                }
            }
        }
    }
}

// ---------------------------------------------------------------------------
// fp32 64x64 GEMM tile with softplus epilogue (dt projection, K=24).
// ---------------------------------------------------------------------------
__device__ __forceinline__ void dt_tile(
    const float* __restrict__ A, int lda,
    const float* __restrict__ W, int ldw,
    const float* __restrict__ bias,
    float* __restrict__ C, int ldc, int K,
    int m0, int n0, DtSh& sh)
{
    int tid = threadIdx.x;
    int tx = tid & 15, ty = tid >> 4;
    float acc[4][4] = {};
    for (int k0 = 0; k0 < K; k0 += 16) {
        {
            int row = tid >> 2;
            int kq  = (tid & 3) * 4;
            const float* ap = A + (size_t)(m0 + row) * lda + k0 + kq;
            float t0 = (k0 + kq + 0 < K) ? ap[0] : 0.f;
            float t1 = (k0 + kq + 1 < K) ? ap[1] : 0.f;
            float t2 = (k0 + kq + 2 < K) ? ap[2] : 0.f;
            float t3 = (k0 + kq + 3 < K) ? ap[3] : 0.f;
            sh.As[kq + 0][row] = t0;
            sh.As[kq + 1][row] = t1;
            sh.As[kq + 2][row] = t2;
            sh.As[kq + 3][row] = t3;
        }
        {
            int krow = tid >> 4;
            int col  = (tid & 15) * 4;
            float4 wv = make_float4(0.f, 0.f, 0.f, 0.f);
            if (k0 + krow < K)
                wv = *(const float4*)(W + (size_t)(k0 + krow) * ldw + n0 + col);
            *(float4*)&sh.Bs[krow][col] = wv;
        }
        __syncthreads();
#pragma unroll
        for (int k = 0; k < 16; k++) {
            float a[4], bv[4];
            *(float4*)a  = *(const float4*)&sh.As[k][ty * 4];
            *(float4*)bv = *(const float4*)&sh.Bs[k][tx * 4];
#pragma unroll
            for (int i = 0; i < 4; i++)
#pragma unroll
                for (int j = 0; j < 4; j++)
                    acc[i][j] = fmaf(a[i], bv[j], acc[i][j]);
        }
        __syncthreads();
    }
#pragma unroll
    for (int i = 0; i < 4; i++) {
        int m = m0 + ty * 4 + i;
#pragma unroll
        for (int j = 0; j < 4; j++) {
            int n = n0 + tx * 4 + j;
            float v = acc[i][j] + bias[n];
            v = (v > 20.f) ? v : log1pf(__expf(v));
            C[(size_t)m * ldc + n] = v;
        }
    }
}

// ---------------------------------------------------------------------------
// Scan unit (thread = channel): chunked selective scan, h[16] in registers.
// ---------------------------------------------------------------------------
template<bool FULL, bool FAST>
__device__ __forceinline__ void scan_run(
    int d, int chunk, int bz, int dir, int bat,
    const float* dt, const ushort* xc, const float* xd, const ushort* xz,
    const float a0, const float* a, float Dd,
    float* h, float* Sp, ushort* yo)
{
    float S = 0.f;
#pragma unroll 2
    for (int i = 0; i < CLEN; i++) {
        int tl = chunk * CLEN + i;
        int t  = dir ? (SEQ - 1 - tl) : tl;
        size_t r = (size_t)(bat * SEQ + t);
        float dtv = dt[r * DINNER + d];
        float xv  = bf2f(xc[r * DINNER + d]);
        const float* bp = xd + r * 56 + DTRANK;
        float4 B0 = *(const float4*)(bp + 0);
        float4 B1 = *(const float4*)(bp + 4);
        float4 B2 = *(const float4*)(bp + 8);
        float4 B3 = *(const float4*)(bp + 12);
        float Bv[16] = {B0.x,B0.y,B0.z,B0.w, B1.x,B1.y,B1.z,B1.w,
                        B2.x,B2.y,B2.z,B2.w, B3.x,B3.y,B3.z,B3.w};
        float w[16];
        if (FAST) {
            float e1 = __expf(dtv * a0);
            float e2 = e1*e1, e4 = e2*e2, e8 = e4*e4;
            w[0]=e1;      w[1]=e2;      w[2]=e2*e1;   w[3]=e4;
            w[4]=e4*e1;   w[5]=e4*e2;   w[6]=e4*w[2]; w[7]=e8;
            w[8]=e8*e1;   w[9]=e8*e2;   w[10]=e8*w[2];w[11]=e8*e4;
            w[12]=e8*w[4];w[13]=e8*w[5];w[14]=e8*w[6];w[15]=e8*e8;
        } else {
#pragma unroll
            for (int n = 0; n < 16; n++) w[n] = __expf(dtv * a[n]);
        }
        float bx = dtv * xv;
#pragma unroll
        for (int n = 0; n < 16; n++)
            h[n] = fmaf(w[n], h[n], bx * Bv[n]);
        S += dtv;
        if (FULL) {
            const float* cp = bp + DSTATE;
            float4 C0 = *(const float4*)(cp + 0);
            float4 C1 = *(const float4*)(cp + 4);
            float4 C2 = *(const float4*)(cp + 8);
            float4 C3 = *(const float4*)(cp + 12);
            float Cv[16] = {C0.x,C0.y,C0.z,C0.w, C1.x,C1.y,C1.z,C1.w,
                            C2.x,C2.y,C2.z,C2.w, C3.x,C3.y,C3.z,C3.w};
            float y = 0.f;
#pragma unroll
            for (int n = 0; n < 16; n++) y = fmaf(h[n], Cv[n], y);
            float zv = bf2f(xz[r * 1536 + DINNER + d]);
            float sig = 1.f / (1.f + __expf(-zv));
            yo[r * DINNER + d] = f2bf((y + xv * Dd) * (zv * sig));
        }
    }
    *Sp = S;
}

template<bool FULL>
__device__ __forceinline__ void scan_unit(
    int u,
    const float* dtf, const ushort* xcf, const float* xdf, const ushort* xzf,
    const float* Alf, const float* Dff,
    const float* dtb, const ushort* xcb, const float* xdb, const ushort* xzb,
    const float* Alb, const float* Dbb,
    float* Hloc, float* Wp, const float* Hin,
    ushort* yf, ushort* yb)
{
    const int d     = (u % 3) * 256 + threadIdx.x;
    const int chunk = (u / 3) % NCH;
    const int bz    = u / (3 * NCH);
    const int dir   = bz >> 1;
    const int bat   = bz & 1;

    const float*  dt = dir ? dtb : dtf;
    const ushort* xc = dir ? xcb : xcf;
    const float*  xd = dir ? xdb : xdf;
    const ushort* xz = dir ? xzb : xzf;
    const float*  Al = dir ? Alb : Alf;
    const float*  Dp = dir ? Dbb : Dff;
    ushort* yo = dir ? yb : yf;

    float a[16];
    {
        const float4* Ap = (const float4*)(Al + (size_t)d * 16);
#pragma unroll
        for (int q = 0; q < 4; q++) {
            float4 v = Ap[q];
            a[q*4+0] = -__expf(v.x); a[q*4+1] = -__expf(v.y);
            a[q*4+2] = -__expf(v.z); a[q*4+3] = -__expf(v.w);
        }
    }
    const float a0 = a[0];
    bool fast = true;
#pragma unroll
    for (int n = 0; n < 16; n++) {
        float ideal = a0 * (float)(n + 1);
        fast = fast && (fabsf(a[n] - ideal) <= 1e-4f * fabsf(ideal) + 1e-7f);
    }

    float h[16];
    if (FULL) {
        size_t base = ((size_t)(bz * NCH + chunk) * DINNER + d) * 16;
#pragma unroll
        for (int q = 0; q < 4; q++) {
            float4 v = *(const float4*)(Hin + base + q * 4);
            h[q*4+0] = v.x; h[q*4+1] = v.y; h[q*4+2] = v.z; h[q*4+3] = v.w;
        }
    } else {
#pragma unroll
        for (int n = 0; n < 16; n++) h[n] = 0.f;
    }
    float Dd = FULL ? Dp[d] : 0.f;
    float S;
    if (fast) scan_run<FULL, true >(d, chunk, bz, dir, bat, dt, xc, xd, xz, a0, a, Dd, h, &S, yo);
    else      scan_run<FULL, false>(d, chunk, bz, dir, bat, dt, xc, xd, xz, a0, a, Dd, h, &S, yo);

    if (!FULL) {
        float W[16];
        if (fast) {
            float E1 = __expf(S * a0);
            float E2 = E1*E1, E4 = E2*E2, E8 = E4*E4;
            W[0]=E1;      W[1]=E2;      W[2]=E2*E1;   W[3]=E4;
            W[4]=E4*E1;   W[5]=E4*E2;   W[6]=E4*W[2]; W[7]=E8;
            W[8]=E8*E1;   W[9]=E8*E2;   W[10]=E8*W[2];W[11]=E8*E4;
            W[12]=E8*W[4];W[13]=E8*W[5];W[14]=E8*W[6];W[15]=E8*E8;
        } else {
#pragma unroll
            for (int n = 0; n < 16; n++) W[n] = __expf(S * a[n]);
        }
        size_t base = ((size_t)(bz * NCH + chunk) * DINNER + d) * 16;
#pragma unroll
        for (int q = 0; q < 4; q++) {
            *(float4*)(Hloc + base + q*4) = make_float4(h[q*4+0], h[q*4+1], h[q*4+2], h[q*4+3]);
            *(float4*)(Wp   + base + q*4) = make_float4(W[q*4+0], W[q*4+1], W[q*4+2], W[q*4+3]);
        }
    }
}

// ---------------------------------------------------------------------------
// Mega kernel: all post-LN phases, separated by device grid barriers.
// ---------------------------------------------------------------------------
struct MegaArgs {
    const float *x, *norm_w, *norm_b;
    const float *ip_b, *f_in_b, *b_in_b, *f_out_b, *b_out_b, *op_b;
    const float *f_conv_w, *f_conv_b, *b_conv_w, *b_conv_b;
    const float *f_dt_w, *f_dt_b, *b_dt_w, *b_dt_b;
    const float *f_A_log, *f_D, *b_A_log, *b_D;
    ushort *xn, *xp, *xzf, *xzb, *xcf, *xcb, *yf, *yb, *cat;
    float *xdf, *xdb, *dtf, *dtb, *outraw;
    float *Hloc, *Wp, *Hin;
    const ushort *Wip, *Wfin, *Wbin, *Wfxp, *Wbxp, *Wfout, *Wbout, *Wop;
    uint *bar;
    float *dout;
};

__global__ __launch_bounds__(256, 3) void mega_kernel(MegaArgs p)
{
    __shared__ MegaSh sh;
    const int blk = blockIdx.x;
    const int tid = threadIdx.x;
    uint* cnt = p.bar;
    uint* gen = p.bar + 1;

    // ---- phase 1: xp = xn @ ip_w + ip_b (384 tiles of 128x64)
    for (int t = blk; t < 384; t += NB)
        gemm_tile<128, 64, true>(p.xn, 768, p.Wip, 768, p.ip_b,
                                 (void*)p.xp, 768, 768, 768,
                                 (t / 12) * 128, (t % 12) * 64, sh.g);
    gbar(cnt, gen);

    // ---- phase 2: xz_{f,b} = xp halves @ in_w + in_b (2x768 tiles)
    for (int t = blk; t < 1536; t += NB) {
        int dir = t >= 768, tt = t - dir * 768;
        gemm_tile<128, 64, true>(p.xp + dir * 384, 768,
                                 dir ? p.Wbin : p.Wfin, 384,
                                 dir ? p.b_in_b : p.f_in_b,
                                 (void*)(dir ? p.xzb : p.xzf), 1536, 1536, 384,
                                 (tt / 24) * 128, (tt % 24) * 64, sh.g);
    }
    gbar(cnt, gen);

    // ---- phase 3: conv + silu (both dirs)
    for (int u = blk; u < 2 * ROWS * DINNER / 256; u += NB) {
        int dir = u >= 12288;
        int idx = (u - dir * 12288) * 256 + tid;
        const ushort* xz = dir ? p.xzb : p.xzf;
        const float* cw = dir ? p.b_conv_w : p.f_conv_w;
        const float* cb = dir ? p.b_conv_b : p.f_conv_b;
        ushort* out = dir ? p.xcb : p.xcf;
        int d = idx % DINNER;
        int row = idx / DINNER;
        int t = row & (SEQ - 1);
        int b = row >> 11;
        float acc = cb[d];
#pragma unroll
        for (int k = 0; k < 4; k++) {
            int ts = dir ? (t + 3 - k) : (t - 3 + k);
            if (ts >= 0 && ts < SEQ)
                acc = fmaf(cw[d * 4 + k], bf2f(xz[((size_t)(b * SEQ + ts)) * 1536 + d]), acc);
        }
        float sig = 1.f / (1.f + __expf(-acc));
        out[idx] = f2bf(acc * sig);
    }
    gbar(cnt, gen);

    // ---- phase 4: xd = xc @ xp_w (64 tiles of 128x64, N=56)
    for (int t = blk; t < 64; t += NB) {
        int dir = t >= 32, tt = t - dir * 32;
        gemm_tile<128, 64, false>(dir ? p.xcb : p.xcf, 768,
                                  dir ? p.Wbxp : p.Wfxp, 768,
                                  (const float*)nullptr,
                                  (void*)(dir ? p.xdb : p.xdf), 56, 56, 768,
                                  tt * 128, 0, sh.g);
    }
    gbar(cnt, gen);

    // ---- phase 5: dt = softplus(xd[:, :24] @ dt_w + dt_b) (2x768 tiles 64x64)
    for (int t = blk; t < 1536; t += NB) {
        int dir = t >= 768, tt = t - dir * 768;
        dt_tile(dir ? p.xdb : p.xdf, 56,
                dir ? p.b_dt_w : p.f_dt_w, 768,
                dir ? p.b_dt_b : p.f_dt_b,
                dir ? p.dtb : p.dtf, 768, DTRANK,
                (tt / 12) * 64, (tt % 12) * 64, sh.d);
    }
    gbar(cnt, gen);

    // ---- phase 6: scan pass 1 (768 units)
    for (int u = blk; u < 768; u += NB)
        scan_unit<false>(u, p.dtf, p.xcf, p.xdf, p.xzf, p.f_A_log, p.f_D,
                         p.dtb, p.xcb, p.xdb, p.xzb, p.b_A_log, p.b_D,
                         p.Hloc, p.Wp, (const float*)nullptr,
                         (ushort*)nullptr, (ushort*)nullptr);
    gbar(cnt, gen);

    // ---- phase 7: combine (192 units)
    for (int u = blk; u < 192; u += NB) {
        int idx = u * 256 + tid;
        int bz = idx / (DINNER * 16);
        int rest = idx % (DINNER * 16);
        float hin = 0.f;
#pragma unroll 4
        for (int k = 0; k < NCH; k++) {
            size_t o = (size_t)(bz * NCH + k) * (DINNER * 16) + rest;
            p.Hin[o] = hin;
            hin = fmaf(p.Wp[o], hin, p.Hloc[o]);
        }
    }
    gbar(cnt, gen);

    // ---- phase 8: scan pass 2 (768 units, fused epilogue)
    for (int u = blk; u < 768; u += NB)
        scan_unit<true>(u, p.dtf, p.xcf, p.xdf, p.xzf, p.f_A_log, p.f_D,
                        p.dtb, p.xcb, p.xdb, p.xzb, p.b_A_log, p.b_D,
                        (float*)nullptr, (float*)nullptr, p.Hin, p.yf, p.yb);
    gbar(cnt, gen);

    // ---- phase 9: out_{f,b} = y @ out_w + out_b -> cat (2x192 tiles)
    for (int t = blk; t < 384; t += NB) {
        int dir = t >= 192, tt = t - dir * 192;
        gemm_tile<128, 64, true>(dir ? p.yb : p.yf, 768,
                                 dir ? p.Wbout : p.Wfout, 768,
                                 dir ? p.b_out_b : p.f_out_b,
                                 (void*)(p.cat + dir * 384), 768, 384, 768,
                                 (tt / 6) * 128, (tt % 6) * 64, sh.g);
    }
    gbar(cnt, gen);

    // ---- phase 10: op projection (384 tiles, fp32 out)
    for (int t = blk; t < 384; t += NB)
        gemm_tile<128, 64, false>(p.cat, 768, p.Wop, 768, p.op_b,
                                  (void*)p.outraw, 768, 768, 768,
                                  (t / 12) * 128, (t % 12) * 64, sh.g);
    gbar(cnt, gen);

    // ---- phase 11: final layernorm(residual + out)
    for (int r = blk; r < ROWS; r += NB)
        ln_row<false>(r, p.x, p.outraw, p.norm_w, p.norm_b, (void*)p.dout, sh.l);
}

// ---------------------------------------------------------------------------
// Prep kernel: weight transpose+cast, input layernorm, barrier init.
// ---------------------------------------------------------------------------
struct TD { const float* src; ushort* dst; int K, N, Np, tile0, tk; };
struct PrepArgs {
    TD d[8];
    int ntc;
    const float *x, *in_nw, *in_nb;
    ushort* xn;
    uint* bar;
};

__global__ __launch_bounds__(256) void prep_kernel(PrepArgs p)
{
    __shared__ union { float tile[32][33]; LnSh l; } sh;
    int bi = blockIdx.x;
    if (bi < p.ntc) {
        int i = 0;
        while (i < 7 && bi >= p.d[i + 1].tile0) i++;
        TD t = p.d[i];
        int local = bi - t.tile0;
        int tk = local % t.tk, tn = local / t.tk;
        int tx = threadIdx.x & 31, ty = threadIdx.x >> 5;
        int k0 = tk * 32, n0 = tn * 32;
#pragma unroll
        for (int r = ty; r < 32; r += 8) {
            int n = n0 + tx;
            sh.tile[r][tx] = (n < t.N) ? t.src[(size_t)(k0 + r) * t.N + n] : 0.f;
        }
        __syncthreads();
#pragma unroll
        for (int r = ty; r < 32; r += 8) {
            int n = n0 + r, k = k0 + tx;
            t.dst[(size_t)n * t.K + k] = f2bf(sh.tile[tx][r]);
        }
    } else if (bi < p.ntc + ROWS) {
        ln_row<true>(bi - p.ntc, p.x, (const float*)nullptr, p.in_nw, p.in_nb,
                     (void*)p.xn, sh.l);
    } else {
        if (threadIdx.x == 0) { p.bar[0] = 0u; p.bar[1] = 0u; }
    }
}

// ---------------------------------------------------------------------------
extern "C" void kernel_launch(void* const* d_in, const int* in_sizes, int n_in,
                              void* d_out, int out_size, void* d_ws, size_t ws_size,
                              hipStream_t stream)
{
    const float* x        = (const float*)d_in[0];
    const float* in_nw    = (const float*)d_in[1];
    const float* in_nb    = (const float*)d_in[2];
    const float* ip_w     = (const float*)d_in[3];
    const float* ip_b     = (const float*)d_in[4];
    const float* f_in_w   = (const float*)d_in[5];
    const float* f_in_b   = (const float*)d_in[6];
    const float* f_conv_w = (const float*)d_in[7];
    const float* f_conv_b = (const float*)d_in[8];
    const float* f_xp_w   = (const float*)d_in[9];
    const float* f_dt_w   = (const float*)d_in[10];
    const float* f_dt_b   = (const float*)d_in[11];
    const float* f_A_log  = (const float*)d_in[12];
    const float* f_D      = (const float*)d_in[13];
    const float* f_out_w  = (const float*)d_in[14];
    const float* f_out_b  = (const float*)d_in[15];
    const float* b_in_w   = (const float*)d_in[16];
    const float* b_in_b   = (const float*)d_in[17];
    const float* b_conv_w = (const float*)d_in[18];
    const float* b_conv_b = (const float*)d_in[19];
    const float* b_xp_w   = (const float*)d_in[20];
    const float* b_dt_w   = (const float*)d_in[21];
    const float* b_dt_b   = (const float*)d_in[22];
    const float* b_A_log  = (const float*)d_in[23];
    const float* b_D      = (const float*)d_in[24];
    const float* b_out_w  = (const float*)d_in[25];
    const float* b_out_b  = (const float*)d_in[26];
    const float* op_w     = (const float*)d_in[27];
    const float* op_b     = (const float*)d_in[28];
    const float* norm_w   = (const float*)d_in[29];
    const float* norm_b   = (const float*)d_in[30];

    size_t off = 0;
    auto alloc = [&](size_t bytes) {
        void* p = (char*)d_ws + off;
        off += (bytes + 255) & ~(size_t)255;
        return p;
    };
    const size_t R = ROWS;
    ushort* xn_bf   = (ushort*)alloc(R * 768 * 2);
    ushort* xp_bf   = (ushort*)alloc(R * 768 * 2);
    ushort* xz_f_bf = (ushort*)alloc(R * 1536 * 2);
    ushort* xz_b_bf = (ushort*)alloc(R * 1536 * 2);
    ushort* xc_f_bf = (ushort*)alloc(R * 768 * 2);
    ushort* xc_b_bf = (ushort*)alloc(R * 768 * 2);
    float*  xd_f    = (float*)alloc(R * 56 * 4);
    float*  xd_b    = (float*)alloc(R * 56 * 4);
    float*  dt_f    = (float*)alloc(R * 768 * 4);
    float*  dt_b    = (float*)alloc(R * 768 * 4);
    ushort* y_f_bf  = (ushort*)alloc(R * 768 * 2);
    ushort* y_b_bf  = (ushort*)alloc(R * 768 * 2);
    ushort* cat_bf  = (ushort*)alloc(R * 768 * 2);
    float*  outraw  = (float*)alloc(R * 768 * 4);
    const size_t SCN = (size_t)4 * NCH * DINNER * 16;
    float* Hloc = (float*)alloc(SCN * 4);
    float* Wpb  = (float*)alloc(SCN * 4);
    float* Hin  = (float*)alloc(SCN * 4);
    ushort* Wt_ip   = (ushort*)alloc((size_t)768 * 768 * 2);
    ushort* Wt_fin  = (ushort*)alloc((size_t)1536 * 384 * 2);
    ushort* Wt_bin  = (ushort*)alloc((size_t)1536 * 384 * 2);
    ushort* Wt_fxp  = (ushort*)alloc((size_t)64 * 768 * 2);
    ushort* Wt_bxp  = (ushort*)alloc((size_t)64 * 768 * 2);
    ushort* Wt_fout = (ushort*)alloc((size_t)384 * 768 * 2);
    ushort* Wt_bout = (ushort*)alloc((size_t)384 * 768 * 2);
    ushort* Wt_op   = (ushort*)alloc((size_t)768 * 768 * 2);
    uint*   bar     = (uint*)alloc(256);

    // ---- prep: tcast + ln1 + barrier init
    PrepArgs pa;
    int tile0 = 0, nd = 0;
    auto add = [&](const float* s, ushort* dst, int K, int N, int Np) {
        pa.d[nd] = TD{s, dst, K, N, Np, tile0, K / 32};
        tile0 += (K / 32) * (Np / 32);
        nd++;
    };
    add(ip_w,    Wt_ip,   768, 768, 768);
    add(f_in_w,  Wt_fin,  384, 1536, 1536);
    add(b_in_w,  Wt_bin,  384, 1536, 1536);
    add(f_xp_w,  Wt_fxp,  768, 56, 64);
    add(b_xp_w,  Wt_bxp,  768, 56, 64);
    add(f_out_w, Wt_fout, 768, 384, 384);
    add(b_out_w, Wt_bout, 768, 384, 384);
    add(op_w,    Wt_op,   768, 768, 768);
    pa.ntc = tile0;
    pa.x = x; pa.in_nw = in_nw; pa.in_nb = in_nb; pa.xn = xn_bf; pa.bar = bar;
    hipLaunchKernelGGL(prep_kernel, dim3(tile0 + ROWS + 1), dim3(256), 0, stream, pa);

    // ---- mega: everything else in one persistent dispatch
    MegaArgs ma;
    ma.x = x; ma.norm_w = norm_w; ma.norm_b = norm_b;
    ma.ip_b = ip_b; ma.f_in_b = f_in_b; ma.b_in_b = b_in_b;
    ma.f_out_b = f_out_b; ma.b_out_b = b_out_b; ma.op_b = op_b;
    ma.f_conv_w = f_conv_w; ma.f_conv_b = f_conv_b;
    ma.b_conv_w = b_conv_w; ma.b_conv_b = b_conv_b;
    ma.f_dt_w = f_dt_w; ma.f_dt_b = f_dt_b; ma.b_dt_w = b_dt_w; ma.b_dt_b = b_dt_b;
    ma.f_A_log = f_A_log; ma.f_D = f_D; ma.b_A_log = b_A_log; ma.b_D = b_D;
    ma.xn = xn_bf; ma.xp = xp_bf; ma.xzf = xz_f_bf; ma.xzb = xz_b_bf;
    ma.xcf = xc_f_bf; ma.xcb = xc_b_bf; ma.yf = y_f_bf; ma.yb = y_b_bf; ma.cat = cat_bf;
    ma.xdf = xd_f; ma.xdb = xd_b; ma.dtf = dt_f; ma.dtb = dt_b; ma.outraw = outraw;
    ma.Hloc = Hloc; ma.Wp = Wpb; ma.Hin = Hin;
    ma.Wip = Wt_ip; ma.Wfin = Wt_fin; ma.Wbin = Wt_bin;
    ma.Wfxp = Wt_fxp; ma.Wbxp = Wt_bxp; ma.Wfout = Wt_fout; ma.Wbout = Wt_bout;
    ma.Wop = Wt_op;
    ma.bar = bar; ma.dout = (float*)d_out;
    hipLaunchKernelGGL(mega_kernel, dim3(NB), dim3(256), 0, stream, ma);
}

// Round 6
// 401.654 us; speedup vs baseline: 6.4471x; 6.4471x over previous
//
#include <hip/hip_runtime.h>
#include <hip/hip_bf16.h>
#include <math.h>
#include <type_traits>

#define BATCH 2
#define SEQ   2048
#define DMODEL 768
#define DIN   384
#define DINNER 768
#define DSTATE 16
#define DTRANK 24
#define ROWS  (BATCH*SEQ)   // 4096
#define NCH   64            // time chunks for the scan
#define CLEN  (SEQ/NCH)     // 32 steps per chunk

using short8  = __attribute__((ext_vector_type(8))) short;
using floatx4 = __attribute__((ext_vector_type(4))) float;

__device__ __forceinline__ ushort f2bf(float f) {
    union { float f; uint u; } v; v.f = f;
    uint r = (v.u + 0x7fffu + ((v.u >> 16) & 1u)) >> 16;
    return (ushort)r;
}
__device__ __forceinline__ float bf2f(ushort h) {
    union { uint u; float f; } v; v.u = ((uint)h) << 16;
    return v.f;
}
__device__ __forceinline__ void async16(const ushort* g, ushort* l) {
    __builtin_amdgcn_global_load_lds(
        (const __attribute__((address_space(1))) void*)g,
        (__attribute__((address_space(3))) void*)l,
        16, 0, 0);
}

// ---------------------------------------------------------------------------
// MFMA GEMM building blocks (m97 staging, BK=64). C = A[M,K] @ Bt[N,K]^T.
// ---------------------------------------------------------------------------
template<int TM, int TN> struct GemmShT { ushort lA[TM * 64]; ushort lB[TN * 64]; };

template<int TM, int TN>
__device__ __forceinline__ void gemm_accum(
    const ushort* __restrict__ A, int lda,
    const ushort* __restrict__ Bt, int ldb,
    int K, int m0, int n0, GemmShT<TM, TN>& sh,
    floatx4 (&acc)[TM / 32][TN / 32])
{
    constexpr int WM = TM / 2, WN = TN / 2;
    constexpr int MT = WM / 16, NT = WN / 16;
    constexpr int AI = TM / 32, BI = TN / 32;
    const int tid = threadIdx.x;
    const int wave = tid >> 6, lane = tid & 63;
    const int wm = wave >> 1, wn = wave & 1;
    const int quad = lane >> 4, l16 = lane & 15;
    const int lrow = lane >> 3, lcol = (lane & 7) * 8;   // 8 rows x 64 shorts / KB

    for (int k0 = 0; k0 < K; k0 += 64) {
#pragma unroll
        for (int i = 0; i < AI; i++) {
            int rb = (wave * AI + i) * 8;
            async16(A + (size_t)(m0 + rb + lrow) * lda + k0 + lcol, &sh.lA[rb * 64]);
        }
#pragma unroll
        for (int i = 0; i < BI; i++) {
            int rb = (wave * BI + i) * 8;
            async16(Bt + (size_t)(n0 + rb + lrow) * ldb + k0 + lcol, &sh.lB[rb * 64]);
        }
        __syncthreads();
#pragma unroll
        for (int ks = 0; ks < 2; ks++) {
            short8 af[MT], bf[NT];
#pragma unroll
            for (int i = 0; i < MT; i++)
                af[i] = *(const short8*)&sh.lA[(wm * WM + i * 16 + l16) * 64 + ks * 32 + quad * 8];
#pragma unroll
            for (int j = 0; j < NT; j++)
                bf[j] = *(const short8*)&sh.lB[(wn * WN + j * 16 + l16) * 64 + ks * 32 + quad * 8];
#pragma unroll
            for (int i = 0; i < MT; i++)
#pragma unroll
                for (int j = 0; j < NT; j++)
                    acc[i][j] = __builtin_amdgcn_mfma_f32_16x16x32_bf16(af[i], bf[j], acc[i][j], 0, 0, 0);
        }
        __syncthreads();
    }
}

template<int TM, int TN, bool OUT_BF>
__device__ __forceinline__ void gemm_epilogue(
    const float* __restrict__ bias, void* __restrict__ C, int ldc, int N,
    int m0, int n0, floatx4 (&acc)[TM / 32][TN / 32])
{
    constexpr int WM = TM / 2, WN = TN / 2;
    constexpr int MT = WM / 16, NT = WN / 16;
    const int tid = threadIdx.x;
    const int wave = tid >> 6, lane = tid & 63;
    const int wm = wave >> 1, wn = wave & 1;
    const int quad = lane >> 4, l16 = lane & 15;
#pragma unroll
    for (int i = 0; i < MT; i++) {
#pragma unroll
        for (int j = 0; j < NT; j++) {
            int row = m0 + wm * WM + i * 16 + quad * 4;
            int col = n0 + wn * WN + j * 16 + l16;
            if (col < N) {
                float bv = bias ? bias[col] : 0.f;
#pragma unroll
                for (int r = 0; r < 4; r++) {
                    float v = acc[i][j][r] + bv;
                    if (OUT_BF) ((ushort*)C)[(size_t)(row + r) * ldc + col] = f2bf(v);
                    else        ((float*)C)[(size_t)(row + r) * ldc + col] = v;
                }
            }
        }
    }
}

// Generic single-pair GEMM kernel; grid.z selects f/b operand sets.
template<int TM, int TN, bool OUT_BF>
__global__ __launch_bounds__(256) void mfma_gemm_k(
    const ushort* __restrict__ A0, const ushort* __restrict__ A1, int lda,
    const ushort* __restrict__ B0, const ushort* __restrict__ B1, int ldb,
    const float* __restrict__ bias0, const float* __restrict__ bias1,
    void* __restrict__ C0, void* __restrict__ C1, int ldc, int N, int K)
{
    __shared__ GemmShT<TM, TN> sh;
    const ushort* A  = blockIdx.z ? A1 : A0;
    const ushort* Bt = blockIdx.z ? B1 : B0;
    const float* bias = blockIdx.z ? bias1 : bias0;
    void* C = blockIdx.z ? C1 : C0;
    floatx4 acc[TM / 32][TN / 32];
#pragma unroll
    for (int i = 0; i < TM / 32; i++)
#pragma unroll
        for (int j = 0; j < TN / 32; j++)
            acc[i][j] = (floatx4){0.f, 0.f, 0.f, 0.f};
    int m0 = blockIdx.y * TM, n0 = blockIdx.x * TN;
    gemm_accum<TM, TN>(A, lda, Bt, ldb, K, m0, n0, sh, acc);
    gemm_epilogue<TM, TN, OUT_BF>(bias, C, ldc, N, m0, n0, acc);
}

// Dual-A GEMM: C = A0@B0^T + A1@B1^T + bias (fused out+op projection).
template<int TM, int TN>
__global__ __launch_bounds__(256) void outop_kernel(
    const ushort* __restrict__ A0, const ushort* __restrict__ B0,
    const ushort* __restrict__ A1, const ushort* __restrict__ B1,
    const float* __restrict__ bias, float* __restrict__ C,
    int lda, int ldb, int ldc, int N, int K)
{
    __shared__ GemmShT<TM, TN> sh;
    floatx4 acc[TM / 32][TN / 32];
#pragma unroll
    for (int i = 0; i < TM / 32; i++)
#pragma unroll
        for (int j = 0; j < TN / 32; j++)
            acc[i][j] = (floatx4){0.f, 0.f, 0.f, 0.f};
    int m0 = blockIdx.y * TM, n0 = blockIdx.x * TN;
    gemm_accum<TM, TN>(A0, lda, B0, ldb, K, m0, n0, sh, acc);
    gemm_accum<TM, TN>(A1, lda, B1, ldb, K, m0, n0, sh, acc);
    gemm_epilogue<TM, TN, false>(bias, (void*)C, ldc, N, m0, n0, acc);
}

// ---------------------------------------------------------------------------
// LayerNorm row helper (+ standalone kernel for the final LN).
// ---------------------------------------------------------------------------
struct LnSh { float ss[4]; float ssq[4]; float m; float rs; };

template<bool OUT_BF>
__device__ __forceinline__ void ln_row(
    int row, const float* __restrict__ x, const float* __restrict__ res,
    const float* __restrict__ w, const float* __restrict__ b,
    void* __restrict__ out, LnSh& sh)
{
    int tid = threadIdx.x;
    const float* xr = x + (size_t)row * DMODEL;
    const float* rr = res ? res + (size_t)row * DMODEL : nullptr;
    float v[3];
    float s = 0.f, sq = 0.f;
#pragma unroll
    for (int j = 0; j < 3; j++) {
        int i = tid + j * 256;
        float val = xr[i];
        if (rr) val += rr[i];
        v[j] = val; s += val; sq += val * val;
    }
#pragma unroll
    for (int off = 32; off; off >>= 1) {
        s  += __shfl_down(s,  off);
        sq += __shfl_down(sq, off);
    }
    int wid = tid >> 6;
    if ((tid & 63) == 0) { sh.ss[wid] = s; sh.ssq[wid] = sq; }
    __syncthreads();
    if (tid == 0) {
        float S  = sh.ss[0] + sh.ss[1] + sh.ss[2] + sh.ss[3];
        float SQ = sh.ssq[0] + sh.ssq[1] + sh.ssq[2] + sh.ssq[3];
        float m  = S * (1.0f / DMODEL);
        float var = SQ * (1.0f / DMODEL) - m * m;
        sh.m = m;
        sh.rs = rsqrtf(var + 1e-5f);
    }
    __syncthreads();
    float m = sh.m, rs = sh.rs;
#pragma unroll
    for (int j = 0; j < 3; j++) {
        int i = tid + j * 256;
        float r = (v[j] - m) * rs * w[i] + b[i];
        if (OUT_BF) ((ushort*)out)[(size_t)row * DMODEL + i] = f2bf(r);
        else        ((float*)out)[(size_t)row * DMODEL + i] = r;
    }
}

__global__ __launch_bounds__(256) void ln2_kernel(
    const float* __restrict__ x, const float* __restrict__ res,
    const float* __restrict__ w, const float* __restrict__ b,
    float* __restrict__ out)
{
    __shared__ LnSh sh;
    ln_row<false>(blockIdx.x, x, res, w, b, (void*)out, sh);
}

// ---------------------------------------------------------------------------
// Prep: weight transpose/cast (mode 0 = transpose, 1 = plain cast) + input LN.
// ---------------------------------------------------------------------------
struct TD { const float* src; ushort* dst; int K, N, Np, tile0, tk, mode; };
struct PrepArgs {
    TD d[8];
    int ntc;
    const float *x, *in_nw, *in_nb;
    ushort* xn;
};

__global__ __launch_bounds__(256) void prep_kernel(PrepArgs p)
{
    __shared__ union { float tile[32][33]; LnSh l; } sh;
    int bi = blockIdx.x;
    if (bi < p.ntc) {
        int i = 0;
        while (i < 7 && bi >= p.d[i + 1].tile0) i++;
        TD t = p.d[i];
        int local = bi - t.tile0;
        int tki = local % t.tk, tn = local / t.tk;
        int k0 = tki * 32, n0 = tn * 32;
        if (t.mode == 0) {
            int tx = threadIdx.x & 31, ty = threadIdx.x >> 5;
#pragma unroll
            for (int r = ty; r < 32; r += 8) {
                int n = n0 + tx;
                sh.tile[r][tx] = (n < t.N) ? t.src[(size_t)(k0 + r) * t.N + n] : 0.f;
            }
            __syncthreads();
#pragma unroll
            for (int r = ty; r < 32; r += 8) {
                int n = n0 + r, k = k0 + tx;
                t.dst[(size_t)n * t.K + k] = f2bf(sh.tile[tx][r]);
            }
        } else {
#pragma unroll
            for (int e = threadIdx.x; e < 1024; e += 256) {
                int r = e >> 5, c = e & 31;
                size_t o = (size_t)(k0 + r) * t.N + n0 + c;
                t.dst[o] = f2bf(t.src[o]);
            }
        }
    } else {
        ln_row<true>(bi - p.ntc, p.x, (const float*)nullptr, p.in_nw, p.in_nb,
                     (void*)p.xn, sh.l);
    }
}

// ---------------------------------------------------------------------------
// Weight-fusion dispatch: Wz{f,b}^T = (ip_w_half @ in_w)^T (bf16 MFMA),
// Wo{f,b}^T = (out_w @ op_w_half)^T, plus folded bias GEMVs (fp32).
// ---------------------------------------------------------------------------
struct WfArgs {
    const ushort *fin, *bin, *opT, *ipc, *fow, *bow;
    ushort *WzF, *WzB, *WoF, *WoB;
    const float *ip_b, *f_in_b, *b_in_b, *f_out_b, *b_out_b, *op_b;
    const float *f_in_w32, *b_in_w32, *op_w32;
    float *bzf, *bzb, *bo;
};

__global__ __launch_bounds__(256) void wfuse_kernel(WfArgs p)
{
    __shared__ GemmShT<128, 64> sh;
    int t = blockIdx.x;
    if (t < 432) {
        const ushort *A, *Bt; ushort* C; int lda, ldb, m0, n0;
        if (t < 144)      { A = p.fin;       lda = 384; Bt = p.ipc;       ldb = 768; C = p.WzF; int u = t;       m0 = (u / 12) * 128; n0 = (u % 12) * 64; }
        else if (t < 288) { A = p.bin;       lda = 384; Bt = p.ipc + 384; ldb = 768; C = p.WzB; int u = t - 144; m0 = (u / 12) * 128; n0 = (u % 12) * 64; }
        else if (t < 360) { A = p.opT;       lda = 768; Bt = p.fow;       ldb = 384; C = p.WoF; int u = t - 288; m0 = (u / 12) * 128; n0 = (u % 12) * 64; }
        else              { A = p.opT + 384; lda = 768; Bt = p.bow;       ldb = 384; C = p.WoB; int u = t - 360; m0 = (u / 12) * 128; n0 = (u % 12) * 64; }
        floatx4 acc[4][2];
#pragma unroll
        for (int i = 0; i < 4; i++)
#pragma unroll
            for (int j = 0; j < 2; j++)
                acc[i][j] = (floatx4){0.f, 0.f, 0.f, 0.f};
        gemm_accum<128, 64>(A, lda, Bt, ldb, 384, m0, n0, sh, acc);
        gemm_epilogue<128, 64, true>((const float*)nullptr, (void*)C, 768, 768, m0, n0, acc);
    } else if (t < 438) {          // bz_f (1536 outputs)
        int n = (t - 432) * 256 + threadIdx.x;
        float acc = p.f_in_b[n];
        for (int j = 0; j < 384; j++)
            acc = fmaf(p.ip_b[j], p.f_in_w32[(size_t)j * 1536 + n], acc);
        p.bzf[n] = acc;
    } else if (t < 444) {          // bz_b
        int n = (t - 438) * 256 + threadIdx.x;
        float acc = p.b_in_b[n];
        for (int j = 0; j < 384; j++)
            acc = fmaf(p.ip_b[384 + j], p.b_in_w32[(size_t)j * 1536 + n], acc);
        p.bzb[n] = acc;
    } else {                        // bo (768 outputs)
        int n = (t - 444) * 256 + threadIdx.x;
        float acc = p.op_b[n];
        for (int j = 0; j < 384; j++)
            acc = fmaf(p.f_out_b[j], p.op_w32[(size_t)j * 768 + n], acc);
        for (int j = 0; j < 384; j++)
            acc = fmaf(p.b_out_b[j], p.op_w32[(size_t)(384 + j) * 768 + n], acc);
        p.bo[n] = acc;
    }
}

// ---------------------------------------------------------------------------
// Causal conv1d (K=4) + SiLU, 8 channels/thread, f/b via blockIdx.y.
// ---------------------------------------------------------------------------
__global__ __launch_bounds__(256) void conv_silu_kernel(
    const ushort* __restrict__ xzf, const ushort* __restrict__ xzb,
    const float* __restrict__ cwf, const float* __restrict__ cbf,
    const float* __restrict__ cwb, const float* __restrict__ cbb,
    ushort* __restrict__ outf, ushort* __restrict__ outb)
{
    int rev = blockIdx.y;
    const ushort* xz = rev ? xzb : xzf;
    const float* cw = rev ? cwb : cwf;
    const float* cb = rev ? cbb : cbf;
    ushort* out = rev ? outb : outf;

    int idx = blockIdx.x * 256 + threadIdx.x;   // 0 .. ROWS*DINNER/8-1
    int dg = idx % (DINNER / 8);
    int row = idx / (DINNER / 8);
    int d0 = dg * 8;
    int t = row & (SEQ - 1), b = row >> 11;
    float acc[8];
#pragma unroll
    for (int c = 0; c < 8; c++) acc[c] = cb[d0 + c];
#pragma unroll
    for (int k = 0; k < 4; k++) {
        int ts = rev ? (t + 3 - k) : (t - 3 + k);
        if (ts >= 0 && ts < SEQ) {
            short8 v = *(const short8*)&xz[((size_t)(b * SEQ + ts)) * 1536 + d0];
#pragma unroll
            for (int c = 0; c < 8; c++)
                acc[c] = fmaf(cw[(d0 + c) * 4 + k], bf2f((ushort)v[c]), acc[c]);
        }
    }
    short8 o;
#pragma unroll
    for (int c = 0; c < 8; c++) {
        float sig = 1.f / (1.f + __expf(-acc[c]));
        o[c] = (short)f2bf(acc[c] * sig);
    }
    *(short8*)&out[(size_t)row * DINNER + d0] = o;
}

// ---------------------------------------------------------------------------
// fp32 GEMM for the tiny K=24 dt projection (softplus), f/b via grid.z.
// ---------------------------------------------------------------------------
#define BM 64
#define BN 64
#define BK 16
__global__ __launch_bounds__(256) void dt_gemm_kernel(
    const float* __restrict__ A0f, const float* __restrict__ A1f, int lda,
    const float* __restrict__ W0, const float* __restrict__ W1, int ldw,
    const float* __restrict__ bias0, const float* __restrict__ bias1,
    float* __restrict__ C0f, float* __restrict__ C1f, int ldc, int K)
{
    const float* A = blockIdx.z ? A1f : A0f;
    const float* W = blockIdx.z ? W1 : W0;
    const float* bias = blockIdx.z ? bias1 : bias0;
    float* C = blockIdx.z ? C1f : C0f;

    __shared__ float As[BK][BM + 4];
    __shared__ float Bs[BK][BN + 4];
    int tid = threadIdx.x;
    int m0 = blockIdx.y * BM;
    int n0 = blockIdx.x * BN;
    int tx = tid & 15, ty = tid >> 4;
    float acc[4][4] = {};

    for (int k0 = 0; k0 < K; k0 += BK) {
        {
            int row = tid >> 2;
            int kq  = (tid & 3) * 4;
            const float* ap = A + (size_t)(m0 + row) * lda + k0 + kq;
            As[kq + 0][row] = (k0 + kq + 0 < K) ? ap[0] : 0.f;
            As[kq + 1][row] = (k0 + kq + 1 < K) ? ap[1] : 0.f;
            As[kq + 2][row] = (k0 + kq + 2 < K) ? ap[2] : 0.f;
            As[kq + 3][row] = (k0 + kq + 3 < K) ? ap[3] : 0.f;
        }
        {
            int krow = tid >> 4;
            int col  = (tid & 15) * 4;
            float4 wv = make_float4(0.f, 0.f, 0.f, 0.f);
            if (k0 + krow < K)
                wv = *(const float4*)(W + (size_t)(k0 + krow) * ldw + n0 + col);
            *(float4*)&Bs[krow][col] = wv;
        }
        __syncthreads();
#pragma unroll
        for (int k = 0; k < BK; k++) {
            float a[4], bv[4];
            *(float4*)a  = *(const float4*)&As[k][ty * 4];
            *(float4*)bv = *(const float4*)&Bs[k][tx * 4];
#pragma unroll
            for (int i = 0; i < 4; i++)
#pragma unroll
                for (int j = 0; j < 4; j++)
                    acc[i][j] = fmaf(a[i], bv[j], acc[i][j]);
        }
        __syncthreads();
    }
#pragma unroll
    for (int i = 0; i < 4; i++) {
        int m = m0 + ty * 4 + i;
#pragma unroll
        for (int j = 0; j < 4; j++) {
            int n = n0 + tx * 4 + j;
            float v = acc[i][j] + bias[n];
            v = (v > 20.f) ? v : log1pf(__expf(v));
            C[(size_t)m * ldc + n] = v;
        }
    }
}

// ---------------------------------------------------------------------------
// Chunked selective scan (NCH=64, CLEN=32). Same math as R2-R4 (verified).
// ---------------------------------------------------------------------------
template<bool FULL>
__global__ __launch_bounds__(256) void scan_chunk_kernel(
    const float* __restrict__ dtf, const ushort* __restrict__ xcf,
    const float* __restrict__ xdf, const ushort* __restrict__ xzf,
    const float* __restrict__ Alf, const float* __restrict__ Dff,
    const float* __restrict__ dtb, const ushort* __restrict__ xcb,
    const float* __restrict__ xdb, const ushort* __restrict__ xzb,
    const float* __restrict__ Alb, const float* __restrict__ Dbb,
    float* __restrict__ Hloc, float* __restrict__ Wp,
    const float* __restrict__ Hin,
    ushort* __restrict__ yf, ushort* __restrict__ yb)
{
    const int d     = blockIdx.x * 256 + threadIdx.x;
    const int chunk = blockIdx.y;
    const int bz    = blockIdx.z;
    const int dir   = bz >> 1;
    const int bat   = bz & 1;

    const float*  dt = dir ? dtb : dtf;
    const ushort* xc = dir ? xcb : xcf;
    const float*  xd = dir ? xdb : xdf;
    const ushort* xz = dir ? xzb : xzf;
    const float*  Al = dir ? Alb : Alf;
    const float*  Dp = dir ? Dbb : Dff;
    ushort* yo = dir ? yb : yf;

    float a[16];
    {
        const float4* Ap = (const float4*)(Al + (size_t)d * 16);
#pragma unroll
        for (int q = 0; q < 4; q++) {
            float4 v = Ap[q];
            a[q*4+0] = -__expf(v.x); a[q*4+1] = -__expf(v.y);
            a[q*4+2] = -__expf(v.z); a[q*4+3] = -__expf(v.w);
        }
    }
    const float a0 = a[0];
    bool fast = true;
#pragma unroll
    for (int n = 0; n < 16; n++) {
        float ideal = a0 * (float)(n + 1);
        fast = fast && (fabsf(a[n] - ideal) <= 1e-4f * fabsf(ideal) + 1e-7f);
    }

    float h[16];
    if (FULL) {
        size_t base = ((size_t)(bz * NCH + chunk) * DINNER + d) * 16;
#pragma unroll
        for (int q = 0; q < 4; q++) {
            float4 v = *(const float4*)(Hin + base + q * 4);
            h[q*4+0] = v.x; h[q*4+1] = v.y; h[q*4+2] = v.z; h[q*4+3] = v.w;
        }
    } else {
#pragma unroll
        for (int n = 0; n < 16; n++) h[n] = 0.f;
    }

    const float Dd = FULL ? Dp[d] : 0.f;
    float S = 0.f;

    auto run = [&](auto FASTC) {
        constexpr bool FAST = decltype(FASTC)::value;
#pragma unroll 2
        for (int i = 0; i < CLEN; i++) {
            int tl = chunk * CLEN + i;
            int t  = dir ? (SEQ - 1 - tl) : tl;
            size_t r = (size_t)(bat * SEQ + t);
            float dtv = dt[r * DINNER + d];
            float xv  = bf2f(xc[r * DINNER + d]);
            const float* bp = xd + r * 56 + DTRANK;
            float4 B0 = *(const float4*)(bp + 0);
            float4 B1 = *(const float4*)(bp + 4);
            float4 B2 = *(const float4*)(bp + 8);
            float4 B3 = *(const float4*)(bp + 12);
            float Bv[16] = {B0.x,B0.y,B0.z,B0.w, B1.x,B1.y,B1.z,B1.w,
                            B2.x,B2.y,B2.z,B2.w, B3.x,B3.y,B3.z,B3.w};
            float w[16];
            if (FAST) {
                float e1 = __expf(dtv * a0);
                float e2 = e1*e1, e4 = e2*e2, e8 = e4*e4;
                w[0]=e1;      w[1]=e2;      w[2]=e2*e1;   w[3]=e4;
                w[4]=e4*e1;   w[5]=e4*e2;   w[6]=e4*w[2]; w[7]=e8;
                w[8]=e8*e1;   w[9]=e8*e2;   w[10]=e8*w[2];w[11]=e8*e4;
                w[12]=e8*w[4];w[13]=e8*w[5];w[14]=e8*w[6];w[15]=e8*e8;
            } else {
#pragma unroll
                for (int n = 0; n < 16; n++) w[n] = __expf(dtv * a[n]);
            }
            float bx = dtv * xv;
#pragma unroll
            for (int n = 0; n < 16; n++)
                h[n] = fmaf(w[n], h[n], bx * Bv[n]);
            S += dtv;
            if (FULL) {
                const float* cp = bp + DSTATE;
                float4 C0 = *(const float4*)(cp + 0);
                float4 C1 = *(const float4*)(cp + 4);
                float4 C2 = *(const float4*)(cp + 8);
                float4 C3 = *(const float4*)(cp + 12);
                float Cv[16] = {C0.x,C0.y,C0.z,C0.w, C1.x,C1.y,C1.z,C1.w,
                                C2.x,C2.y,C2.z,C2.w, C3.x,C3.y,C3.z,C3.w};
                float y = 0.f;
#pragma unroll
                for (int n = 0; n < 16; n++) y = fmaf(h[n], Cv[n], y);
                float zv = bf2f(xz[r * 1536 + DINNER + d]);
                float sig = 1.f / (1.f + __expf(-zv));
                yo[r * DINNER + d] = f2bf((y + xv * Dd) * (zv * sig));
            }
        }
    };
    if (fast) run(std::true_type{}); else run(std::false_type{});

    if (!FULL) {
        float W[16];
        if (fast) {
            float E1 = __expf(S * a0);
            float E2 = E1*E1, E4 = E2*E2, E8 = E4*E4;
            W[0]=E1;      W[1]=E2;      W[2]=E2*E1;   W[3]=E4;
            W[4]=E4*E1;   W[5]=E4*E2;   W[6]=E4*W[2]; W[7]=E8;
            W[8]=E8*E1;   W[9]=E8*E2;   W[10]=E8*W[2];W[11]=E8*E4;
            W[12]=E8*W[4];W[13]=E8*W[5];W[14]=E8*W[6];W[15]=E8*E8;
        } else {
#pragma unroll
            for (int n = 0; n < 16; n++) W[n] = __expf(S * a[n]);
        }
        size_t base = ((size_t)(bz * NCH + chunk) * DINNER + d) * 16;
#pragma unroll
        for (int q = 0; q < 4; q++) {
            *(float4*)(Hloc + base + q*4) = make_float4(h[q*4+0], h[q*4+1], h[q*4+2], h[q*4+3]);
            *(float4*)(Wp   + base + q*4) = make_float4(W[q*4+0], W[q*4+1], W[q*4+2], W[q*4+3]);
        }
    }
}

__global__ __launch_bounds__(256) void scan_combine(
    const float* __restrict__ Hloc, const float* __restrict__ Wp,
    float* __restrict__ Hin)
{
    int idx = blockIdx.x * 256 + threadIdx.x;
    int bz = idx / (DINNER * 16);
    int rest = idx % (DINNER * 16);
    float hin = 0.f;
#pragma unroll 4
    for (int k = 0; k < NCH; k++) {
        size_t o = (size_t)(bz * NCH + k) * (DINNER * 16) + rest;
        Hin[o] = hin;
        hin = fmaf(Wp[o], hin, Hloc[o]);
    }
}

// ---------------------------------------------------------------------------
extern "C" void kernel_launch(void* const* d_in, const int* in_sizes, int n_in,
                              void* d_out, int out_size, void* d_ws, size_t ws_size,
                              hipStream_t stream)
{
    const float* x        = (const float*)d_in[0];
    const float* in_nw    = (const float*)d_in[1];
    const float* in_nb    = (const float*)d_in[2];
    const float* ip_w     = (const float*)d_in[3];
    const float* ip_b     = (const float*)d_in[4];
    const float* f_in_w   = (const float*)d_in[5];
    const float* f_in_b   = (const float*)d_in[6];
    const float* f_conv_w = (const float*)d_in[7];
    const float* f_conv_b = (const float*)d_in[8];
    const float* f_xp_w   = (const float*)d_in[9];
    const float* f_dt_w   = (const float*)d_in[10];
    const float* f_dt_b   = (const float*)d_in[11];
    const float* f_A_log  = (const float*)d_in[12];
    const float* f_D      = (const float*)d_in[13];
    const float* f_out_w  = (const float*)d_in[14];
    const float* f_out_b  = (const float*)d_in[15];
    const float* b_in_w   = (const float*)d_in[16];
    const float* b_in_b   = (const float*)d_in[17];
    const float* b_conv_w = (const float*)d_in[18];
    const float* b_conv_b = (const float*)d_in[19];
    const float* b_xp_w   = (const float*)d_in[20];
    const float* b_dt_w   = (const float*)d_in[21];
    const float* b_dt_b   = (const float*)d_in[22];
    const float* b_A_log  = (const float*)d_in[23];
    const float* b_D      = (const float*)d_in[24];
    const float* b_out_w  = (const float*)d_in[25];
    const float* b_out_b  = (const float*)d_in[26];
    const float* op_w     = (const float*)d_in[27];
    const float* op_b     = (const float*)d_in[28];
    const float* norm_w   = (const float*)d_in[29];
    const float* norm_b   = (const float*)d_in[30];

    size_t off = 0;
    auto alloc = [&](size_t bytes) {
        void* p = (char*)d_ws + off;
        off += (bytes + 255) & ~(size_t)255;
        return p;
    };
    const size_t R = ROWS;
    ushort* xn_bf   = (ushort*)alloc(R * 768 * 2);
    ushort* xz_f_bf = (ushort*)alloc(R * 1536 * 2);
    ushort* xz_b_bf = (ushort*)alloc(R * 1536 * 2);
    ushort* xc_f_bf = (ushort*)alloc(R * 768 * 2);
    ushort* xc_b_bf = (ushort*)alloc(R * 768 * 2);
    float*  xd_f    = (float*)alloc(R * 56 * 4);
    float*  xd_b    = (float*)alloc(R * 56 * 4);
    float*  dt_f    = (float*)alloc(R * 768 * 4);
    float*  dt_b    = (float*)alloc(R * 768 * 4);
    ushort* y_f_bf  = (ushort*)alloc(R * 768 * 2);
    ushort* y_b_bf  = (ushort*)alloc(R * 768 * 2);
    float*  outraw  = (float*)alloc(R * 768 * 4);
    const size_t SCN = (size_t)4 * NCH * DINNER * 16;
    float* Hloc = (float*)alloc(SCN * 4);
    float* Wpb  = (float*)alloc(SCN * 4);
    float* Hin  = (float*)alloc(SCN * 4);
    ushort* Wt_fin = (ushort*)alloc((size_t)1536 * 384 * 2);
    ushort* Wt_bin = (ushort*)alloc((size_t)1536 * 384 * 2);
    ushort* Wt_op  = (ushort*)alloc((size_t)768 * 768 * 2);
    ushort* Wt_fxp = (ushort*)alloc((size_t)64 * 768 * 2);
    ushort* Wt_bxp = (ushort*)alloc((size_t)64 * 768 * 2);
    ushort* ipc    = (ushort*)alloc((size_t)768 * 768 * 2);
    ushort* fow    = (ushort*)alloc((size_t)768 * 384 * 2);
    ushort* bow    = (ushort*)alloc((size_t)768 * 384 * 2);
    ushort* WzF    = (ushort*)alloc((size_t)1536 * 768 * 2);
    ushort* WzB    = (ushort*)alloc((size_t)1536 * 768 * 2);
    ushort* WoF    = (ushort*)alloc((size_t)768 * 768 * 2);
    ushort* WoB    = (ushort*)alloc((size_t)768 * 768 * 2);
    float*  bzf    = (float*)alloc(1536 * 4);
    float*  bzb    = (float*)alloc(1536 * 4);
    float*  bo     = (float*)alloc(768 * 4);

    // ---- D1: prep (tcast + ln1) ----
    PrepArgs pa;
    int tile0 = 0, nd = 0;
    auto add = [&](const float* s, ushort* dst, int K, int N, int Np, int mode) {
        int tiles = mode == 0 ? (K / 32) * (Np / 32) : (K / 32) * (N / 32);
        pa.d[nd] = TD{s, dst, K, N, Np, tile0, K / 32, mode};
        tile0 += tiles;
        nd++;
    };
    add(f_in_w,  Wt_fin, 384, 1536, 1536, 0);
    add(b_in_w,  Wt_bin, 384, 1536, 1536, 0);
    add(op_w,    Wt_op,  768, 768, 768, 0);
    add(f_xp_w,  Wt_fxp, 768, 56, 64, 0);
    add(b_xp_w,  Wt_bxp, 768, 56, 64, 0);
    add(ip_w,    ipc,    768, 768, 768, 1);
    add(f_out_w, fow,    768, 384, 384, 1);
    add(b_out_w, bow,    768, 384, 384, 1);
    pa.ntc = tile0;
    pa.x = x; pa.in_nw = in_nw; pa.in_nb = in_nb; pa.xn = xn_bf;
    hipLaunchKernelGGL(prep_kernel, dim3(tile0 + ROWS), dim3(256), 0, stream, pa);

    // ---- D2: weight fusion ----
    WfArgs wa;
    wa.fin = Wt_fin; wa.bin = Wt_bin; wa.opT = Wt_op;
    wa.ipc = ipc; wa.fow = fow; wa.bow = bow;
    wa.WzF = WzF; wa.WzB = WzB; wa.WoF = WoF; wa.WoB = WoB;
    wa.ip_b = ip_b; wa.f_in_b = f_in_b; wa.b_in_b = b_in_b;
    wa.f_out_b = f_out_b; wa.b_out_b = b_out_b; wa.op_b = op_b;
    wa.f_in_w32 = f_in_w; wa.b_in_w32 = b_in_w; wa.op_w32 = op_w;
    wa.bzf = bzf; wa.bzb = bzb; wa.bo = bo;
    hipLaunchKernelGGL(wfuse_kernel, dim3(447), dim3(256), 0, stream, wa);

    // ---- D3: xz_{f,b} = xn @ Wz + bz (K=768, ip fused away) ----
    hipLaunchKernelGGL((mfma_gemm_k<128, 128, true>), dim3(12, 32, 2), dim3(256), 0, stream,
                       xn_bf, xn_bf, 768, WzF, WzB, 768, bzf, bzb,
                       (void*)xz_f_bf, (void*)xz_b_bf, 1536, 1536, 768);

    // ---- D4: conv + silu ----
    hipLaunchKernelGGL(conv_silu_kernel, dim3(ROWS * DINNER / 8 / 256, 2), dim3(256), 0, stream,
                       xz_f_bf, xz_b_bf, f_conv_w, f_conv_b, b_conv_w, b_conv_b,
                       xc_f_bf, xc_b_bf);

    // ---- D5: xd = xc @ xp_w (N=56 pad 64) ----
    hipLaunchKernelGGL((mfma_gemm_k<128, 64, false>), dim3(1, 32, 2), dim3(256), 0, stream,
                       xc_f_bf, xc_b_bf, 768, Wt_fxp, Wt_bxp, 768,
                       (const float*)nullptr, (const float*)nullptr,
                       (void*)xd_f, (void*)xd_b, 56, 56, 768);

    // ---- D6: dt = softplus(xd[:, :24] @ dt_w + dt_b) ----
    hipLaunchKernelGGL(dt_gemm_kernel, dim3(768 / BN, ROWS / BM, 2), dim3(256), 0, stream,
                       xd_f, xd_b, 56, f_dt_w, b_dt_w, 768, f_dt_b, b_dt_b,
                       dt_f, dt_b, 768, DTRANK);

    // ---- D7/D8/D9: chunked selective scan ----
    hipLaunchKernelGGL((scan_chunk_kernel<false>), dim3(DINNER / 256, NCH, 4), dim3(256), 0, stream,
                       dt_f, xc_f_bf, xd_f, xz_f_bf, f_A_log, f_D,
                       dt_b, xc_b_bf, xd_b, xz_b_bf, b_A_log, b_D,
                       Hloc, Wpb, (const float*)nullptr, (ushort*)nullptr, (ushort*)nullptr);
    hipLaunchKernelGGL(scan_combine, dim3(4 * DINNER * 16 / 256), dim3(256), 0, stream,
                       Hloc, Wpb, Hin);
    hipLaunchKernelGGL((scan_chunk_kernel<true>), dim3(DINNER / 256, NCH, 4), dim3(256), 0, stream,
                       dt_f, xc_f_bf, xd_f, xz_f_bf, f_A_log, f_D,
                       dt_b, xc_b_bf, xd_b, xz_b_bf, b_A_log, b_D,
                       (float*)nullptr, (float*)nullptr, Hin, y_f_bf, y_b_bf);

    // ---- D10: outraw = y_f @ WoF + y_b @ WoB + bo (out+op fused) ----
    hipLaunchKernelGGL((outop_kernel<128, 64>), dim3(12, 32), dim3(256), 0, stream,
                       y_f_bf, WoF, y_b_bf, WoB, bo, outraw, 768, 768, 768, 768, 768);

    // ---- D11: final layernorm(residual + out) ----
    hipLaunchKernelGGL(ln2_kernel, dim3(ROWS), dim3(256), 0, stream,
                       x, outraw, norm_w, norm_b, (float*)d_out);
}

// Round 7
// 364.879 us; speedup vs baseline: 7.0968x; 1.1008x over previous
//
#include <hip/hip_runtime.h>
#include <hip/hip_bf16.h>
#include <math.h>
#include <type_traits>

#define BATCH 2
#define SEQ   2048
#define DMODEL 768
#define DIN   384
#define DINNER 768
#define DSTATE 16
#define DTRANK 24
#define ROWS  (BATCH*SEQ)   // 4096
#define NCH   64            // time chunks for the scan
#define CLEN  (SEQ/NCH)     // 32 steps per chunk

using short8  = __attribute__((ext_vector_type(8))) short;
using floatx4 = __attribute__((ext_vector_type(4))) float;

__device__ __forceinline__ ushort f2bf(float f) {
    union { float f; uint u; } v; v.f = f;
    uint r = (v.u + 0x7fffu + ((v.u >> 16) & 1u)) >> 16;
    return (ushort)r;
}
__device__ __forceinline__ float bf2f(ushort h) {
    union { uint u; float f; } v; v.u = ((uint)h) << 16;
    return v.f;
}
__device__ __forceinline__ void async16(const ushort* g, ushort* l) {
    __builtin_amdgcn_global_load_lds(
        (const __attribute__((address_space(1))) void*)g,
        (__attribute__((address_space(3))) void*)l,
        16, 0, 0);
}

// ---------------------------------------------------------------------------
// MFMA GEMM building blocks (m97 staging, BK=64, XOR-swizzled LDS).
// Physical granule p of row r holds logical granule p^(r&7); staging lane i
// therefore fetches global granule (i&7)^(i>>3) of its row -- zero cost.
// Fragment reads then land 2-way-per-bank (free) instead of 16-way.
// ---------------------------------------------------------------------------
template<int TM, int TN> struct GemmShT { ushort lA[TM * 64]; ushort lB[TN * 64]; };

template<int TM, int TN>
__device__ __forceinline__ void gemm_accum(
    const ushort* __restrict__ A, int lda,
    const ushort* __restrict__ Bt, int ldb,
    int K, int m0, int n0, GemmShT<TM, TN>& sh,
    floatx4 (&acc)[TM / 32][TN / 32])
{
    constexpr int WM = TM / 2, WN = TN / 2;
    constexpr int MT = WM / 16, NT = WN / 16;
    constexpr int AI = TM / 32, BI = TN / 32;
    const int tid = threadIdx.x;
    const int wave = tid >> 6, lane = tid & 63;
    const int wm = wave >> 1, wn = wave & 1;
    const int quad = lane >> 4, l16 = lane & 15;
    const int lrow = lane >> 3;                      // 8 rows per 1KB wave-store
    const int lcol = ((lane & 7) ^ (lane >> 3)) * 8; // XOR-swizzled source granule

    for (int k0 = 0; k0 < K; k0 += 64) {
#pragma unroll
        for (int i = 0; i < AI; i++) {
            int rb = (wave * AI + i) * 8;
            async16(A + (size_t)(m0 + rb + lrow) * lda + k0 + lcol, &sh.lA[rb * 64]);
        }
#pragma unroll
        for (int i = 0; i < BI; i++) {
            int rb = (wave * BI + i) * 8;
            async16(Bt + (size_t)(n0 + rb + lrow) * ldb + k0 + lcol, &sh.lB[rb * 64]);
        }
        __syncthreads();
#pragma unroll
        for (int ks = 0; ks < 2; ks++) {
            short8 af[MT], bf[NT];
#pragma unroll
            for (int i = 0; i < MT; i++) {
                int row = wm * WM + i * 16 + l16;
                af[i] = *(const short8*)&sh.lA[row * 64 + ((ks * 4 + quad) ^ (row & 7)) * 8];
            }
#pragma unroll
            for (int j = 0; j < NT; j++) {
                int row = wn * WN + j * 16 + l16;
                bf[j] = *(const short8*)&sh.lB[row * 64 + ((ks * 4 + quad) ^ (row & 7)) * 8];
            }
#pragma unroll
            for (int i = 0; i < MT; i++)
#pragma unroll
                for (int j = 0; j < NT; j++)
                    acc[i][j] = __builtin_amdgcn_mfma_f32_16x16x32_bf16(af[i], bf[j], acc[i][j], 0, 0, 0);
        }
        __syncthreads();
    }
}

template<int TM, int TN, bool OUT_BF>
__device__ __forceinline__ void gemm_epilogue(
    const float* __restrict__ bias, void* __restrict__ C, int ldc, int N,
    int m0, int n0, floatx4 (&acc)[TM / 32][TN / 32])
{
    constexpr int WM = TM / 2, WN = TN / 2;
    constexpr int MT = WM / 16, NT = WN / 16;
    const int tid = threadIdx.x;
    const int wave = tid >> 6, lane = tid & 63;
    const int wm = wave >> 1, wn = wave & 1;
    const int quad = lane >> 4, l16 = lane & 15;
#pragma unroll
    for (int i = 0; i < MT; i++) {
#pragma unroll
        for (int j = 0; j < NT; j++) {
            int row = m0 + wm * WM + i * 16 + quad * 4;
            int col = n0 + wn * WN + j * 16 + l16;
            if (col < N) {
                float bv = bias ? bias[col] : 0.f;
#pragma unroll
                for (int r = 0; r < 4; r++) {
                    float v = acc[i][j][r] + bv;
                    if (OUT_BF) ((ushort*)C)[(size_t)(row + r) * ldc + col] = f2bf(v);
                    else        ((float*)C)[(size_t)(row + r) * ldc + col] = v;
                }
            }
        }
    }
}

// Generic single-pair GEMM kernel; grid.z selects f/b operand sets.
template<int TM, int TN, bool OUT_BF>
__global__ __launch_bounds__(256) void mfma_gemm_k(
    const ushort* __restrict__ A0, const ushort* __restrict__ A1, int lda,
    const ushort* __restrict__ B0, const ushort* __restrict__ B1, int ldb,
    const float* __restrict__ bias0, const float* __restrict__ bias1,
    void* __restrict__ C0, void* __restrict__ C1, int ldc, int N, int K)
{
    __shared__ GemmShT<TM, TN> sh;
    const ushort* A  = blockIdx.z ? A1 : A0;
    const ushort* Bt = blockIdx.z ? B1 : B0;
    const float* bias = blockIdx.z ? bias1 : bias0;
    void* C = blockIdx.z ? C1 : C0;
    floatx4 acc[TM / 32][TN / 32];
#pragma unroll
    for (int i = 0; i < TM / 32; i++)
#pragma unroll
        for (int j = 0; j < TN / 32; j++)
            acc[i][j] = (floatx4){0.f, 0.f, 0.f, 0.f};
    int m0 = blockIdx.y * TM, n0 = blockIdx.x * TN;
    gemm_accum<TM, TN>(A, lda, Bt, ldb, K, m0, n0, sh, acc);
    gemm_epilogue<TM, TN, OUT_BF>(bias, C, ldc, N, m0, n0, acc);
}

// Combined xd+dt GEMM: A=xc[4096x768], Bt=Wcomb[832x768].
// cols 0..55 -> xd fp32; cols 64..831 -> softplus(v+dt_b) -> dt fp32.
__global__ __launch_bounds__(256) void xddt_kernel(
    const ushort* __restrict__ xcf, const ushort* __restrict__ xcb,
    const ushort* __restrict__ Wcf, const ushort* __restrict__ Wcb,
    const float* __restrict__ dtbf, const float* __restrict__ dtbb,
    float* __restrict__ xdf, float* __restrict__ xdb,
    float* __restrict__ dtf, float* __restrict__ dtb)
{
    constexpr int TM = 128, TN = 64;
    __shared__ GemmShT<TM, TN> sh;
    const ushort* A  = blockIdx.z ? xcb : xcf;
    const ushort* Bt = blockIdx.z ? Wcb : Wcf;
    const float* dbias = blockIdx.z ? dtbb : dtbf;
    float* xd = blockIdx.z ? xdb : xdf;
    float* dt = blockIdx.z ? dtb : dtf;
    floatx4 acc[4][2];
#pragma unroll
    for (int i = 0; i < 4; i++)
#pragma unroll
        for (int j = 0; j < 2; j++)
            acc[i][j] = (floatx4){0.f, 0.f, 0.f, 0.f};
    int m0 = blockIdx.y * TM, n0 = blockIdx.x * TN;
    gemm_accum<TM, TN>(A, 768, Bt, 768, 768, m0, n0, sh, acc);
    const int tid = threadIdx.x;
    const int wave = tid >> 6, lane = tid & 63;
    const int wm = wave >> 1, wn = wave & 1;
    const int quad = lane >> 4, l16 = lane & 15;
#pragma unroll
    for (int i = 0; i < 4; i++) {
#pragma unroll
        for (int j = 0; j < 2; j++) {
            int row = m0 + wm * 64 + i * 16 + quad * 4;
            int col = n0 + wn * 32 + j * 16 + l16;
            if (col < 56) {
#pragma unroll
                for (int r = 0; r < 4; r++)
                    xd[(size_t)(row + r) * 56 + col] = acc[i][j][r];
            } else if (col >= 64) {
                int jj = col - 64;
                float bv = dbias[jj];
#pragma unroll
                for (int r = 0; r < 4; r++) {
                    float v = acc[i][j][r] + bv;
                    v = (v > 20.f) ? v : log1pf(__expf(v));
                    dt[(size_t)(row + r) * 768 + jj] = v;
                }
            }
        }
    }
}

// Dual-A GEMM: C = A0@B0^T + A1@B1^T + bias (fused out+op projection).
template<int TM, int TN>
__global__ __launch_bounds__(256) void outop_kernel(
    const ushort* __restrict__ A0, const ushort* __restrict__ B0,
    const ushort* __restrict__ A1, const ushort* __restrict__ B1,
    const float* __restrict__ bias, float* __restrict__ C,
    int lda, int ldb, int ldc, int N, int K)
{
    __shared__ GemmShT<TM, TN> sh;
    floatx4 acc[TM / 32][TN / 32];
#pragma unroll
    for (int i = 0; i < TM / 32; i++)
#pragma unroll
        for (int j = 0; j < TN / 32; j++)
            acc[i][j] = (floatx4){0.f, 0.f, 0.f, 0.f};
    int m0 = blockIdx.y * TM, n0 = blockIdx.x * TN;
    gemm_accum<TM, TN>(A0, lda, B0, ldb, K, m0, n0, sh, acc);
    gemm_accum<TM, TN>(A1, lda, B1, ldb, K, m0, n0, sh, acc);
    gemm_epilogue<TM, TN, false>(bias, (void*)C, ldc, N, m0, n0, acc);
}

// ---------------------------------------------------------------------------
// LayerNorm row helper (+ standalone kernel for the final LN).
// ---------------------------------------------------------------------------
struct LnSh { float ss[4]; float ssq[4]; float m; float rs; };

template<bool OUT_BF>
__device__ __forceinline__ void ln_row(
    int row, const float* __restrict__ x, const float* __restrict__ res,
    const float* __restrict__ w, const float* __restrict__ b,
    void* __restrict__ out, LnSh& sh)
{
    int tid = threadIdx.x;
    const float* xr = x + (size_t)row * DMODEL;
    const float* rr = res ? res + (size_t)row * DMODEL : nullptr;
    float v[3];
    float s = 0.f, sq = 0.f;
#pragma unroll
    for (int j = 0; j < 3; j++) {
        int i = tid + j * 256;
        float val = xr[i];
        if (rr) val += rr[i];
        v[j] = val; s += val; sq += val * val;
    }
#pragma unroll
    for (int off = 32; off; off >>= 1) {
        s  += __shfl_down(s,  off);
        sq += __shfl_down(sq, off);
    }
    int wid = tid >> 6;
    if ((tid & 63) == 0) { sh.ss[wid] = s; sh.ssq[wid] = sq; }
    __syncthreads();
    if (tid == 0) {
        float S  = sh.ss[0] + sh.ss[1] + sh.ss[2] + sh.ss[3];
        float SQ = sh.ssq[0] + sh.ssq[1] + sh.ssq[2] + sh.ssq[3];
        float m  = S * (1.0f / DMODEL);
        float var = SQ * (1.0f / DMODEL) - m * m;
        sh.m = m;
        sh.rs = rsqrtf(var + 1e-5f);
    }
    __syncthreads();
    float m = sh.m, rs = sh.rs;
#pragma unroll
    for (int j = 0; j < 3; j++) {
        int i = tid + j * 256;
        float r = (v[j] - m) * rs * w[i] + b[i];
        if (OUT_BF) ((ushort*)out)[(size_t)row * DMODEL + i] = f2bf(r);
        else        ((float*)out)[(size_t)row * DMODEL + i] = r;
    }
}

__global__ __launch_bounds__(256) void ln2_kernel(
    const float* __restrict__ x, const float* __restrict__ res,
    const float* __restrict__ w, const float* __restrict__ b,
    float* __restrict__ out)
{
    __shared__ LnSh sh;
    ln_row<false>(blockIdx.x, x, res, w, b, (void*)out, sh);
}

// ---------------------------------------------------------------------------
// Prep: weight transpose/cast with zero-padding + input LN.
// mode 0: dst[n*ldd + k] = src[k*N + n] (transpose); tiles over Kp/32 x Np/32
// mode 1: dst[k*ldd + n] = src[k*N + n] (cast);      same tiling
// OOB (k>=K or n>=N) writes 0.
// ---------------------------------------------------------------------------
struct TD { const float* src; ushort* dst; int K, N, Kp, Np, ldd, tile0, tkp, mode; };
struct PrepArgs {
    TD d[12];
    int ntc;
    const float *x, *in_nw, *in_nb;
    ushort* xn;
};

__global__ __launch_bounds__(256) void prep_kernel(PrepArgs p)
{
    __shared__ union { float tile[32][33]; LnSh l; } sh;
    int bi = blockIdx.x;
    if (bi < p.ntc) {
        int i = 0;
        while (i < 11 && bi >= p.d[i + 1].tile0) i++;
        TD t = p.d[i];
        int local = bi - t.tile0;
        int tki = local % t.tkp, tn = local / t.tkp;
        int k0 = tki * 32, n0 = tn * 32;
        if (t.mode == 0) {
            int tx = threadIdx.x & 31, ty = threadIdx.x >> 5;
#pragma unroll
            for (int r = ty; r < 32; r += 8) {
                int k = k0 + r, n = n0 + tx;
                sh.tile[r][tx] = (k < t.K && n < t.N) ? t.src[(size_t)k * t.N + n] : 0.f;
            }
            __syncthreads();
#pragma unroll
            for (int r = ty; r < 32; r += 8) {
                int n = n0 + r, k = k0 + tx;
                t.dst[(size_t)n * t.ldd + k] = f2bf(sh.tile[tx][r]);
            }
        } else {
#pragma unroll
            for (int e = threadIdx.x; e < 1024; e += 256) {
                int r = e >> 5, c = e & 31;
                int k = k0 + r, n = n0 + c;
                float v = (k < t.K && n < t.N) ? t.src[(size_t)k * t.N + n] : 0.f;
                t.dst[(size_t)k * t.ldd + n] = f2bf(v);
            }
        }
    } else {
        ln_row<true>(bi - p.ntc, p.x, (const float*)nullptr, p.in_nw, p.in_nb,
                     (void*)p.xn, sh.l);
    }
}

// ---------------------------------------------------------------------------
// Weight-fusion dispatch:
//   WzT = (ip_half @ in_w)^T       [1536 x 768]  (t < 288 f, < 432 b... below)
//   WoT = (out_w @ op_half)^T      [768 x 768]
//   WdtT = (xp_w[:, :24] @ dt_w)^T [768 x 768] -> Wcomb rows 64..831
//   + folded bias GEMVs (fp32).
// ---------------------------------------------------------------------------
struct WfArgs {
    const ushort *fin, *bin, *opT, *ipc, *fow, *bow;
    const ushort *dtwTf, *dtwTb, *xpcf, *xpcb;
    ushort *WzF, *WzB, *WoF, *WoB, *WcF, *WcB;
    const float *ip_b, *f_in_b, *b_in_b, *f_out_b, *b_out_b, *op_b;
    const float *f_in_w32, *b_in_w32, *op_w32;
    float *bzf, *bzb, *bo;
};

__global__ __launch_bounds__(256) void wfuse_kernel(WfArgs p)
{
    __shared__ GemmShT<128, 64> sh;
    int t = blockIdx.x;
    if (t < 576) {
        const ushort *A, *Bt; ushort* C; int lda, ldb, K, m0, n0;
        if (t < 144)      { A = p.fin;   lda = 384; Bt = p.ipc;       ldb = 768; K = 384; C = p.WzF;           int u = t;       m0 = (u / 12) * 128; n0 = (u % 12) * 64; }
        else if (t < 288) { A = p.bin;   lda = 384; Bt = p.ipc + 384; ldb = 768; K = 384; C = p.WzB;           int u = t - 144; m0 = (u / 12) * 128; n0 = (u % 12) * 64; }
        else if (t < 360) { A = p.opT;   lda = 768; Bt = p.fow;       ldb = 384; K = 384; C = p.WoF;           int u = t - 288; m0 = (u / 12) * 128; n0 = (u % 12) * 64; }
        else if (t < 432) { A = p.opT + 384; lda = 768; Bt = p.bow;   ldb = 384; K = 384; C = p.WoB;           int u = t - 360; m0 = (u / 12) * 128; n0 = (u % 12) * 64; }
        else if (t < 504) { A = p.dtwTf; lda = 64;  Bt = p.xpcf;      ldb = 64;  K = 64;  C = p.WcF + 64*768;  int u = t - 432; m0 = (u / 12) * 128; n0 = (u % 12) * 64; }
        else              { A = p.dtwTb; lda = 64;  Bt = p.xpcb;      ldb = 64;  K = 64;  C = p.WcB + 64*768;  int u = t - 504; m0 = (u / 12) * 128; n0 = (u % 12) * 64; }
        floatx4 acc[4][2];
#pragma unroll
        for (int i = 0; i < 4; i++)
#pragma unroll
            for (int j = 0; j < 2; j++)
                acc[i][j] = (floatx4){0.f, 0.f, 0.f, 0.f};
        gemm_accum<128, 64>(A, lda, Bt, ldb, K, m0, n0, sh, acc);
        gemm_epilogue<128, 64, true>((const float*)nullptr, (void*)C, 768, 768, m0, n0, acc);
    } else if (t < 582) {          // bz_f (1536 outputs)
        int n = (t - 576) * 256 + threadIdx.x;
        float acc = p.f_in_b[n];
        for (int j = 0; j < 384; j++)
            acc = fmaf(p.ip_b[j], p.f_in_w32[(size_t)j * 1536 + n], acc);
        p.bzf[n] = acc;
    } else if (t < 588) {          // bz_b
        int n = (t - 582) * 256 + threadIdx.x;
        float acc = p.b_in_b[n];
        for (int j = 0; j < 384; j++)
            acc = fmaf(p.ip_b[384 + j], p.b_in_w32[(size_t)j * 1536 + n], acc);
        p.bzb[n] = acc;
    } else {                        // bo (768 outputs)
        int n = (t - 588) * 256 + threadIdx.x;
        float acc = p.op_b[n];
        for (int j = 0; j < 384; j++)
            acc = fmaf(p.f_out_b[j], p.op_w32[(size_t)j * 768 + n], acc);
        for (int j = 0; j < 384; j++)
            acc = fmaf(p.b_out_b[j], p.op_w32[(size_t)(384 + j) * 768 + n], acc);
        p.bo[n] = acc;
    }
}

// ---------------------------------------------------------------------------
// Causal conv1d (K=4) + SiLU, one element/thread (R4 structure), float4 cw.
// ---------------------------------------------------------------------------
__global__ __launch_bounds__(256) void conv_silu_kernel(
    const ushort* __restrict__ xzf, const ushort* __restrict__ xzb,
    const float* __restrict__ cwf, const float* __restrict__ cbf,
    const float* __restrict__ cwb, const float* __restrict__ cbb,
    ushort* __restrict__ outf, ushort* __restrict__ outb)
{
    int rev = blockIdx.y;
    const ushort* xz = rev ? xzb : xzf;
    const float* cw = rev ? cwb : cwf;
    const float* cb = rev ? cbb : cbf;
    ushort* out = rev ? outb : outf;

    int idx = blockIdx.x * 256 + threadIdx.x;
    int d = idx % DINNER;
    int row = idx / DINNER;
    int t = row & (SEQ - 1), b = row >> 11;
    float4 w4 = *(const float4*)&cw[d * 4];
    float wk[4] = {w4.x, w4.y, w4.z, w4.w};
    float acc = cb[d];
#pragma unroll
    for (int k = 0; k < 4; k++) {
        int ts = rev ? (t + 3 - k) : (t - 3 + k);
        if (ts >= 0 && ts < SEQ)
            acc = fmaf(wk[k], bf2f(xz[((size_t)(b * SEQ + ts)) * 1536 + d]), acc);
    }
    float sig = 1.f / (1.f + __expf(-acc));
    out[idx] = f2bf(acc * sig);
}

// ---------------------------------------------------------------------------
// Chunked selective scan (NCH=64, CLEN=32). Same math as R2-R6 (verified).
// ---------------------------------------------------------------------------
template<bool FULL>
__global__ __launch_bounds__(256) void scan_chunk_kernel(
    const float* __restrict__ dtf, const ushort* __restrict__ xcf,
    const float* __restrict__ xdf, const ushort* __restrict__ xzf,
    const float* __restrict__ Alf, const float* __restrict__ Dff,
    const float* __restrict__ dtb, const ushort* __restrict__ xcb,
    const float* __restrict__ xdb, const ushort* __restrict__ xzb,
    const float* __restrict__ Alb, const float* __restrict__ Dbb,
    float* __restrict__ Hloc, float* __restrict__ Wp,
    const float* __restrict__ Hin,
    ushort* __restrict__ yf, ushort* __restrict__ yb)
{
    const int d     = blockIdx.x * 256 + threadIdx.x;
    const int chunk = blockIdx.y;
    const int bz    = blockIdx.z;
    const int dir   = bz >> 1;
    const int bat   = bz & 1;

    const float*  dt = dir ? dtb : dtf;
    const ushort* xc = dir ? xcb : xcf;
    const float*  xd = dir ? xdb : xdf;
    const ushort* xz = dir ? xzb : xzf;
    const float*  Al = dir ? Alb : Alf;
    const float*  Dp = dir ? Dbb : Dff;
    ushort* yo = dir ? yb : yf;

    float a[16];
    {
        const float4* Ap = (const float4*)(Al + (size_t)d * 16);
#pragma unroll
        for (int q = 0; q < 4; q++) {
            float4 v = Ap[q];
            a[q*4+0] = -__expf(v.x); a[q*4+1] = -__expf(v.y);
            a[q*4+2] = -__expf(v.z); a[q*4+3] = -__expf(v.w);
        }
    }
    const float a0 = a[0];
    bool fast = true;
#pragma unroll
    for (int n = 0; n < 16; n++) {
        float ideal = a0 * (float)(n + 1);
        fast = fast && (fabsf(a[n] - ideal) <= 1e-4f * fabsf(ideal) + 1e-7f);
    }

    float h[16];
    if (FULL) {
        size_t base = ((size_t)(bz * NCH + chunk) * DINNER + d) * 16;
#pragma unroll
        for (int q = 0; q < 4; q++) {
            float4 v = *(const float4*)(Hin + base + q * 4);
            h[q*4+0] = v.x; h[q*4+1] = v.y; h[q*4+2] = v.z; h[q*4+3] = v.w;
        }
    } else {
#pragma unroll
        for (int n = 0; n < 16; n++) h[n] = 0.f;
    }

    const float Dd = FULL ? Dp[d] : 0.f;
    float S = 0.f;

    auto run = [&](auto FASTC) {
        constexpr bool FAST = decltype(FASTC)::value;
#pragma unroll 2
        for (int i = 0; i < CLEN; i++) {
            int tl = chunk * CLEN + i;
            int t  = dir ? (SEQ - 1 - tl) : tl;
            size_t r = (size_t)(bat * SEQ + t);
            float dtv = dt[r * DINNER + d];
            float xv  = bf2f(xc[r * DINNER + d]);
            const float* bp = xd + r * 56 + DTRANK;
            float4 B0 = *(const float4*)(bp + 0);
            float4 B1 = *(const float4*)(bp + 4);
            float4 B2 = *(const float4*)(bp + 8);
            float4 B3 = *(const float4*)(bp + 12);
            float Bv[16] = {B0.x,B0.y,B0.z,B0.w, B1.x,B1.y,B1.z,B1.w,
                            B2.x,B2.y,B2.z,B2.w, B3.x,B3.y,B3.z,B3.w};
            float w[16];
            if (FAST) {
                float e1 = __expf(dtv * a0);
                float e2 = e1*e1, e4 = e2*e2, e8 = e4*e4;
                w[0]=e1;      w[1]=e2;      w[2]=e2*e1;   w[3]=e4;
                w[4]=e4*e1;   w[5]=e4*e2;   w[6]=e4*w[2]; w[7]=e8;
                w[8]=e8*e1;   w[9]=e8*e2;   w[10]=e8*w[2];w[11]=e8*e4;
                w[12]=e8*w[4];w[13]=e8*w[5];w[14]=e8*w[6];w[15]=e8*e8;
            } else {
#pragma unroll
                for (int n = 0; n < 16; n++) w[n] = __expf(dtv * a[n]);
            }
            float bx = dtv * xv;
#pragma unroll
            for (int n = 0; n < 16; n++)
                h[n] = fmaf(w[n], h[n], bx * Bv[n]);
            S += dtv;
            if (FULL) {
                const float* cp = bp + DSTATE;
                float4 C0 = *(const float4*)(cp + 0);
                float4 C1 = *(const float4*)(cp + 4);
                float4 C2 = *(const float4*)(cp + 8);
                float4 C3 = *(const float4*)(cp + 12);
                float Cv[16] = {C0.x,C0.y,C0.z,C0.w, C1.x,C1.y,C1.z,C1.w,
                                C2.x,C2.y,C2.z,C2.w, C3.x,C3.y,C3.z,C3.w};
                float y = 0.f;
#pragma unroll
                for (int n = 0; n < 16; n++) y = fmaf(h[n], Cv[n], y);
                float zv = bf2f(xz[r * 1536 + DINNER + d]);
                float sig = 1.f / (1.f + __expf(-zv));
                yo[r * DINNER + d] = f2bf((y + xv * Dd) * (zv * sig));
            }
        }
    };
    if (fast) run(std::true_type{}); else run(std::false_type{});

    if (!FULL) {
        float W[16];
        if (fast) {
            float E1 = __expf(S * a0);
            float E2 = E1*E1, E4 = E2*E2, E8 = E4*E4;
            W[0]=E1;      W[1]=E2;      W[2]=E2*E1;   W[3]=E4;
            W[4]=E4*E1;   W[5]=E4*E2;   W[6]=E4*W[2]; W[7]=E8;
            W[8]=E8*E1;   W[9]=E8*E2;   W[10]=E8*W[2];W[11]=E8*E4;
            W[12]=E8*W[4];W[13]=E8*W[5];W[14]=E8*W[6];W[15]=E8*E8;
        } else {
#pragma unroll
            for (int n = 0; n < 16; n++) W[n] = __expf(S * a[n]);
        }
        size_t base = ((size_t)(bz * NCH + chunk) * DINNER + d) * 16;
#pragma unroll
        for (int q = 0; q < 4; q++) {
            *(float4*)(Hloc + base + q*4) = make_float4(h[q*4+0], h[q*4+1], h[q*4+2], h[q*4+3]);
            *(float4*)(Wp   + base + q*4) = make_float4(W[q*4+0], W[q*4+1], W[q*4+2], W[q*4+3]);
        }
    }
}

__global__ __launch_bounds__(256) void scan_combine(
    const float* __restrict__ Hloc, const float* __restrict__ Wp,
    float* __restrict__ Hin)
{
    int idx = blockIdx.x * 256 + threadIdx.x;
    int bz = idx / (DINNER * 16);
    int rest = idx % (DINNER * 16);
    float hin = 0.f;
#pragma unroll 4
    for (int k = 0; k < NCH; k++) {
        size_t o = (size_t)(bz * NCH + k) * (DINNER * 16) + rest;
        Hin[o] = hin;
        hin = fmaf(Wp[o], hin, Hloc[o]);
    }
}

// ---------------------------------------------------------------------------
extern "C" void kernel_launch(void* const* d_in, const int* in_sizes, int n_in,
                              void* d_out, int out_size, void* d_ws, size_t ws_size,
                              hipStream_t stream)
{
    const float* x        = (const float*)d_in[0];
    const float* in_nw    = (const float*)d_in[1];
    const float* in_nb    = (const float*)d_in[2];
    const float* ip_w     = (const float*)d_in[3];
    const float* ip_b     = (const float*)d_in[4];
    const float* f_in_w   = (const float*)d_in[5];
    const float* f_in_b   = (const float*)d_in[6];
    const float* f_conv_w = (const float*)d_in[7];
    const float* f_conv_b = (const float*)d_in[8];
    const float* f_xp_w   = (const float*)d_in[9];
    const float* f_dt_w   = (const float*)d_in[10];
    const float* f_dt_b   = (const float*)d_in[11];
    const float* f_A_log  = (const float*)d_in[12];
    const float* f_D      = (const float*)d_in[13];
    const float* f_out_w  = (const float*)d_in[14];
    const float* f_out_b  = (const float*)d_in[15];
    const float* b_in_w   = (const float*)d_in[16];
    const float* b_in_b   = (const float*)d_in[17];
    const float* b_conv_w = (const float*)d_in[18];
    const float* b_conv_b = (const float*)d_in[19];
    const float* b_xp_w   = (const float*)d_in[20];
    const float* b_dt_w   = (const float*)d_in[21];
    const float* b_dt_b   = (const float*)d_in[22];
    const float* b_A_log  = (const float*)d_in[23];
    const float* b_D      = (const float*)d_in[24];
    const float* b_out_w  = (const float*)d_in[25];
    const float* b_out_b  = (const float*)d_in[26];
    const float* op_w     = (const float*)d_in[27];
    const float* op_b     = (const float*)d_in[28];
    const float* norm_w   = (const float*)d_in[29];
    const float* norm_b   = (const float*)d_in[30];

    size_t off = 0;
    auto alloc = [&](size_t bytes) {
        void* p = (char*)d_ws + off;
        off += (bytes + 255) & ~(size_t)255;
        return p;
    };
    const size_t R = ROWS;
    ushort* xn_bf   = (ushort*)alloc(R * 768 * 2);
    ushort* xz_f_bf = (ushort*)alloc(R * 1536 * 2);
    ushort* xz_b_bf = (ushort*)alloc(R * 1536 * 2);
    ushort* xc_f_bf = (ushort*)alloc(R * 768 * 2);
    ushort* xc_b_bf = (ushort*)alloc(R * 768 * 2);
    float*  xd_f    = (float*)alloc(R * 56 * 4);
    float*  xd_b    = (float*)alloc(R * 56 * 4);
    float*  dt_f    = (float*)alloc(R * 768 * 4);
    float*  dt_b    = (float*)alloc(R * 768 * 4);
    ushort* y_f_bf  = (ushort*)alloc(R * 768 * 2);
    ushort* y_b_bf  = (ushort*)alloc(R * 768 * 2);
    float*  outraw  = (float*)alloc(R * 768 * 4);
    const size_t SCN = (size_t)4 * NCH * DINNER * 16;
    float* Hloc = (float*)alloc(SCN * 4);
    float* Wpb  = (float*)alloc(SCN * 4);
    float* Hin  = (float*)alloc(SCN * 4);
    ushort* Wt_fin = (ushort*)alloc((size_t)1536 * 384 * 2);
    ushort* Wt_bin = (ushort*)alloc((size_t)1536 * 384 * 2);
    ushort* Wt_op  = (ushort*)alloc((size_t)768 * 768 * 2);
    ushort* ipc    = (ushort*)alloc((size_t)768 * 768 * 2);
    ushort* fow    = (ushort*)alloc((size_t)768 * 384 * 2);
    ushort* bow    = (ushort*)alloc((size_t)768 * 384 * 2);
    ushort* dtwT_f = (ushort*)alloc((size_t)768 * 64 * 2);
    ushort* dtwT_b = (ushort*)alloc((size_t)768 * 64 * 2);
    ushort* xpc_f  = (ushort*)alloc((size_t)768 * 64 * 2);
    ushort* xpc_b  = (ushort*)alloc((size_t)768 * 64 * 2);
    ushort* WzF    = (ushort*)alloc((size_t)1536 * 768 * 2);
    ushort* WzB    = (ushort*)alloc((size_t)1536 * 768 * 2);
    ushort* WoF    = (ushort*)alloc((size_t)768 * 768 * 2);
    ushort* WoB    = (ushort*)alloc((size_t)768 * 768 * 2);
    ushort* WcF    = (ushort*)alloc((size_t)832 * 768 * 2);
    ushort* WcB    = (ushort*)alloc((size_t)832 * 768 * 2);
    float*  bzf    = (float*)alloc(1536 * 4);
    float*  bzb    = (float*)alloc(1536 * 4);
    float*  bo     = (float*)alloc(768 * 4);

    // ---- D1: prep (tcast + ln1) ----
    PrepArgs pa;
    int tile0 = 0, nd = 0;
    auto add = [&](const float* s, ushort* dst, int K, int N, int Kp, int Np,
                   int ldd, int mode) {
        pa.d[nd] = TD{s, dst, K, N, Kp, Np, ldd, tile0, Kp / 32, mode};
        tile0 += (Kp / 32) * (Np / 32);
        nd++;
    };
    add(f_in_w,  Wt_fin,      384, 1536, 384, 1536, 384, 0);
    add(b_in_w,  Wt_bin,      384, 1536, 384, 1536, 384, 0);
    add(op_w,    Wt_op,       768, 768,  768, 768,  768, 0);
    add(f_xp_w,  WcF,         768, 56,   768, 64,   768, 0);  // Wcomb_f rows 0..63
    add(b_xp_w,  WcB,         768, 56,   768, 64,   768, 0);
    add(f_dt_w,  dtwT_f,      24,  768,  64,  768,  64,  0);  // zero-padded K
    add(b_dt_w,  dtwT_b,      24,  768,  64,  768,  64,  0);
    add(ip_w,    ipc,         768, 768,  768, 768,  768, 1);
    add(f_out_w, fow,         768, 384,  768, 384,  384, 1);
    add(b_out_w, bow,         768, 384,  768, 384,  384, 1);
    add(f_xp_w,  xpc_f,       768, 56,   768, 64,   64,  1);  // row-padded cast
    add(b_xp_w,  xpc_b,       768, 56,   768, 64,   64,  1);
    pa.ntc = tile0;
    pa.x = x; pa.in_nw = in_nw; pa.in_nb = in_nb; pa.xn = xn_bf;
    hipLaunchKernelGGL(prep_kernel, dim3(tile0 + ROWS), dim3(256), 0, stream, pa);

    // ---- D2: weight fusion ----
    WfArgs wa;
    wa.fin = Wt_fin; wa.bin = Wt_bin; wa.opT = Wt_op;
    wa.ipc = ipc; wa.fow = fow; wa.bow = bow;
    wa.dtwTf = dtwT_f; wa.dtwTb = dtwT_b; wa.xpcf = xpc_f; wa.xpcb = xpc_b;
    wa.WzF = WzF; wa.WzB = WzB; wa.WoF = WoF; wa.WoB = WoB; wa.WcF = WcF; wa.WcB = WcB;
    wa.ip_b = ip_b; wa.f_in_b = f_in_b; wa.b_in_b = b_in_b;
    wa.f_out_b = f_out_b; wa.b_out_b = b_out_b; wa.op_b = op_b;
    wa.f_in_w32 = f_in_w; wa.b_in_w32 = b_in_w; wa.op_w32 = op_w;
    wa.bzf = bzf; wa.bzb = bzb; wa.bo = bo;
    hipLaunchKernelGGL(wfuse_kernel, dim3(591), dim3(256), 0, stream, wa);

    // ---- D3: xz_{f,b} = xn @ Wz + bz (K=768) ----
    hipLaunchKernelGGL((mfma_gemm_k<128, 128, true>), dim3(12, 32, 2), dim3(256), 0, stream,
                       xn_bf, xn_bf, 768, WzF, WzB, 768, bzf, bzb,
                       (void*)xz_f_bf, (void*)xz_b_bf, 1536, 1536, 768);

    // ---- D4: conv + silu ----
    hipLaunchKernelGGL(conv_silu_kernel, dim3(ROWS * DINNER / 256, 2), dim3(256), 0, stream,
                       xz_f_bf, xz_b_bf, f_conv_w, f_conv_b, b_conv_w, b_conv_b,
                       xc_f_bf, xc_b_bf);

    // ---- D5: xd + dt = xc @ Wcomb (split epilogue, softplus on dt part) ----
    hipLaunchKernelGGL(xddt_kernel, dim3(13, 32, 2), dim3(256), 0, stream,
                       xc_f_bf, xc_b_bf, WcF, WcB, f_dt_b, b_dt_b,
                       xd_f, xd_b, dt_f, dt_b);

    // ---- D6/D7/D8: chunked selective scan ----
    hipLaunchKernelGGL((scan_chunk_kernel<false>), dim3(DINNER / 256, NCH, 4), dim3(256), 0, stream,
                       dt_f, xc_f_bf, xd_f, xz_f_bf, f_A_log, f_D,
                       dt_b, xc_b_bf, xd_b, xz_b_bf, b_A_log, b_D,
                       Hloc, Wpb, (const float*)nullptr, (ushort*)nullptr, (ushort*)nullptr);
    hipLaunchKernelGGL(scan_combine, dim3(4 * DINNER * 16 / 256), dim3(256), 0, stream,
                       Hloc, Wpb, Hin);
    hipLaunchKernelGGL((scan_chunk_kernel<true>), dim3(DINNER / 256, NCH, 4), dim3(256), 0, stream,
                       dt_f, xc_f_bf, xd_f, xz_f_bf, f_A_log, f_D,
                       dt_b, xc_b_bf, xd_b, xz_b_bf, b_A_log, b_D,
                       (float*)nullptr, (float*)nullptr, Hin, y_f_bf, y_b_bf);

    // ---- D9: outraw = y_f @ WoF + y_b @ WoB + bo ----
    hipLaunchKernelGGL((outop_kernel<128, 64>), dim3(12, 32), dim3(256), 0, stream,
                       y_f_bf, WoF, y_b_bf, WoB, bo, outraw, 768, 768, 768, 768, 768);

    // ---- D10: final layernorm(residual + out) ----
    hipLaunchKernelGGL(ln2_kernel, dim3(ROWS), dim3(256), 0, stream,
                       x, outraw, norm_w, norm_b, (float*)d_out);
}

// Round 8
// 331.496 us; speedup vs baseline: 7.8115x; 1.1007x over previous
//
#include <hip/hip_runtime.h>
#include <hip/hip_bf16.h>
#include <math.h>
#include <type_traits>

#define BATCH 2
#define SEQ   2048
#define DMODEL 768
#define DIN   384
#define DINNER 768
#define DSTATE 16
#define DTRANK 24
#define ROWS  (BATCH*SEQ)   // 4096
#define NCH   64            // time chunks for the scan
#define CLEN  (SEQ/NCH)     // 32 steps per chunk

using short8  = __attribute__((ext_vector_type(8))) short;
using floatx4 = __attribute__((ext_vector_type(4))) float;

__device__ __forceinline__ ushort f2bf(float f) {
    union { float f; uint u; } v; v.f = f;
    uint r = (v.u + 0x7fffu + ((v.u >> 16) & 1u)) >> 16;
    return (ushort)r;
}
__device__ __forceinline__ float bf2f(ushort h) {
    union { uint u; float f; } v; v.u = ((uint)h) << 16;
    return v.f;
}
__device__ __forceinline__ void async16(const ushort* g, ushort* l) {
    __builtin_amdgcn_global_load_lds(
        (const __attribute__((address_space(1))) void*)g,
        (__attribute__((address_space(3))) void*)l,
        16, 0, 0);
}
// softplus via fast HW transcendentals (v_exp_f32 + v_log_f32), not log1pf
__device__ __forceinline__ float softplus_fast(float v) {
    if (v > 20.f) return v;
    float e = __expf(-fabsf(v));
    return fmaxf(v, 0.f) + __logf(1.f + e);
}

// ---------------------------------------------------------------------------
// MFMA GEMM building blocks (m97 staging, BK=64, XOR-swizzled LDS).
// Physical granule p of row r holds logical granule p^(r&7); staging lane i
// fetches global granule (i&7)^(i>>3) of its row (zero cost). Fragment reads
// land 2-way-per-bank (free). [R7: conflicts 7.1M -> 0]
// ---------------------------------------------------------------------------
template<int TM, int TN> struct GemmShT { ushort lA[TM * 64]; ushort lB[TN * 64]; };

template<int TM, int TN>
__device__ __forceinline__ void gemm_accum(
    const ushort* __restrict__ A, int lda,
    const ushort* __restrict__ Bt, int ldb,
    int K, int m0, int n0, GemmShT<TM, TN>& sh,
    floatx4 (&acc)[TM / 32][TN / 32])
{
    constexpr int WM = TM / 2, WN = TN / 2;
    constexpr int MT = WM / 16, NT = WN / 16;
    constexpr int AI = TM / 32, BI = TN / 32;
    const int tid = threadIdx.x;
    const int wave = tid >> 6, lane = tid & 63;
    const int wm = wave >> 1, wn = wave & 1;
    const int quad = lane >> 4, l16 = lane & 15;
    const int lrow = lane >> 3;                      // 8 rows per 1KB wave-store
    const int lcol = ((lane & 7) ^ (lane >> 3)) * 8; // XOR-swizzled source granule

    for (int k0 = 0; k0 < K; k0 += 64) {
#pragma unroll
        for (int i = 0; i < AI; i++) {
            int rb = (wave * AI + i) * 8;
            async16(A + (size_t)(m0 + rb + lrow) * lda + k0 + lcol, &sh.lA[rb * 64]);
        }
#pragma unroll
        for (int i = 0; i < BI; i++) {
            int rb = (wave * BI + i) * 8;
            async16(Bt + (size_t)(n0 + rb + lrow) * ldb + k0 + lcol, &sh.lB[rb * 64]);
        }
        __syncthreads();
#pragma unroll
        for (int ks = 0; ks < 2; ks++) {
            short8 af[MT], bf[NT];
#pragma unroll
            for (int i = 0; i < MT; i++) {
                int row = wm * WM + i * 16 + l16;
                af[i] = *(const short8*)&sh.lA[row * 64 + ((ks * 4 + quad) ^ (row & 7)) * 8];
            }
#pragma unroll
            for (int j = 0; j < NT; j++) {
                int row = wn * WN + j * 16 + l16;
                bf[j] = *(const short8*)&sh.lB[row * 64 + ((ks * 4 + quad) ^ (row & 7)) * 8];
            }
#pragma unroll
            for (int i = 0; i < MT; i++)
#pragma unroll
                for (int j = 0; j < NT; j++)
                    acc[i][j] = __builtin_amdgcn_mfma_f32_16x16x32_bf16(af[i], bf[j], acc[i][j], 0, 0, 0);
        }
        __syncthreads();
    }
}

template<int TM, int TN, bool OUT_BF>
__device__ __forceinline__ void gemm_epilogue(
    const float* __restrict__ bias, void* __restrict__ C, int ldc, int N,
    int m0, int n0, floatx4 (&acc)[TM / 32][TN / 32])
{
    constexpr int WM = TM / 2, WN = TN / 2;
    constexpr int MT = WM / 16, NT = WN / 16;
    const int tid = threadIdx.x;
    const int wave = tid >> 6, lane = tid & 63;
    const int wm = wave >> 1, wn = wave & 1;
    const int quad = lane >> 4, l16 = lane & 15;
#pragma unroll
    for (int i = 0; i < MT; i++) {
#pragma unroll
        for (int j = 0; j < NT; j++) {
            int row = m0 + wm * WM + i * 16 + quad * 4;
            int col = n0 + wn * WN + j * 16 + l16;
            if (col < N) {
                float bv = bias ? bias[col] : 0.f;
#pragma unroll
                for (int r = 0; r < 4; r++) {
                    float v = acc[i][j][r] + bv;
                    if (OUT_BF) ((ushort*)C)[(size_t)(row + r) * ldc + col] = f2bf(v);
                    else        ((float*)C)[(size_t)(row + r) * ldc + col] = v;
                }
            }
        }
    }
}

// Generic single-pair GEMM kernel; grid.z selects f/b operand sets.
template<int TM, int TN, bool OUT_BF>
__global__ __launch_bounds__(256) void mfma_gemm_k(
    const ushort* __restrict__ A0, const ushort* __restrict__ A1, int lda,
    const ushort* __restrict__ B0, const ushort* __restrict__ B1, int ldb,
    const float* __restrict__ bias0, const float* __restrict__ bias1,
    void* __restrict__ C0, void* __restrict__ C1, int ldc, int N, int K)
{
    __shared__ GemmShT<TM, TN> sh;
    const ushort* A  = blockIdx.z ? A1 : A0;
    const ushort* Bt = blockIdx.z ? B1 : B0;
    const float* bias = blockIdx.z ? bias1 : bias0;
    void* C = blockIdx.z ? C1 : C0;
    floatx4 acc[TM / 32][TN / 32];
#pragma unroll
    for (int i = 0; i < TM / 32; i++)
#pragma unroll
        for (int j = 0; j < TN / 32; j++)
            acc[i][j] = (floatx4){0.f, 0.f, 0.f, 0.f};
    int m0 = blockIdx.y * TM, n0 = blockIdx.x * TN;
    gemm_accum<TM, TN>(A, lda, Bt, ldb, K, m0, n0, sh, acc);
    gemm_epilogue<TM, TN, OUT_BF>(bias, C, ldc, N, m0, n0, acc);
}

// dt = softplus(xd64 @ dtwT^T + dt_b). K=64 (dt_w zero-padded rows 24..63
// annihilate the B/C columns of xd64). Fast-softplus epilogue, fp32 out.
__global__ __launch_bounds__(256) void dt_kernel(
    const ushort* __restrict__ xdf, const ushort* __restrict__ xdb,
    const ushort* __restrict__ dtwTf, const ushort* __restrict__ dtwTb,
    const float* __restrict__ dtbf, const float* __restrict__ dtbb,
    float* __restrict__ dtf, float* __restrict__ dtb)
{
    constexpr int TM = 128, TN = 64;
    __shared__ GemmShT<TM, TN> sh;
    const ushort* A  = blockIdx.z ? xdb : xdf;
    const ushort* Bt = blockIdx.z ? dtwTb : dtwTf;
    const float* bias = blockIdx.z ? dtbb : dtbf;
    float* C = blockIdx.z ? dtb : dtf;
    floatx4 acc[4][2];
#pragma unroll
    for (int i = 0; i < 4; i++)
#pragma unroll
        for (int j = 0; j < 2; j++)
            acc[i][j] = (floatx4){0.f, 0.f, 0.f, 0.f};
    int m0 = blockIdx.y * TM, n0 = blockIdx.x * TN;
    gemm_accum<TM, TN>(A, 64, Bt, 64, 64, m0, n0, sh, acc);
    const int tid = threadIdx.x;
    const int wave = tid >> 6, lane = tid & 63;
    const int wm = wave >> 1, wn = wave & 1;
    const int quad = lane >> 4, l16 = lane & 15;
#pragma unroll
    for (int i = 0; i < 4; i++) {
#pragma unroll
        for (int j = 0; j < 2; j++) {
            int row = m0 + wm * 64 + i * 16 + quad * 4;
            int col = n0 + wn * 32 + j * 16 + l16;
            float bv = bias[col];
#pragma unroll
            for (int r = 0; r < 4; r++)
                C[(size_t)(row + r) * 768 + col] = softplus_fast(acc[i][j][r] + bv);
        }
    }
}

// Dual-A GEMM: C = A0@B0^T + A1@B1^T + bias (fused out+op projection).
template<int TM, int TN>
__global__ __launch_bounds__(256) void outop_kernel(
    const ushort* __restrict__ A0, const ushort* __restrict__ B0,
    const ushort* __restrict__ A1, const ushort* __restrict__ B1,
    const float* __restrict__ bias, float* __restrict__ C,
    int lda, int ldb, int ldc, int N, int K)
{
    __shared__ GemmShT<TM, TN> sh;
    floatx4 acc[TM / 32][TN / 32];
#pragma unroll
    for (int i = 0; i < TM / 32; i++)
#pragma unroll
        for (int j = 0; j < TN / 32; j++)
            acc[i][j] = (floatx4){0.f, 0.f, 0.f, 0.f};
    int m0 = blockIdx.y * TM, n0 = blockIdx.x * TN;
    gemm_accum<TM, TN>(A0, lda, B0, ldb, K, m0, n0, sh, acc);
    gemm_accum<TM, TN>(A1, lda, B1, ldb, K, m0, n0, sh, acc);
    gemm_epilogue<TM, TN, false>(bias, (void*)C, ldc, N, m0, n0, acc);
}

// ---------------------------------------------------------------------------
// LayerNorm row helper (+ standalone kernel for the final LN).
// ---------------------------------------------------------------------------
struct LnSh { float ss[4]; float ssq[4]; float m; float rs; };

template<bool OUT_BF>
__device__ __forceinline__ void ln_row(
    int row, const float* __restrict__ x, const float* __restrict__ res,
    const float* __restrict__ w, const float* __restrict__ b,
    void* __restrict__ out, LnSh& sh)
{
    int tid = threadIdx.x;
    const float* xr = x + (size_t)row * DMODEL;
    const float* rr = res ? res + (size_t)row * DMODEL : nullptr;
    float v[3];
    float s = 0.f, sq = 0.f;
#pragma unroll
    for (int j = 0; j < 3; j++) {
        int i = tid + j * 256;
        float val = xr[i];
        if (rr) val += rr[i];
        v[j] = val; s += val; sq += val * val;
    }
#pragma unroll
    for (int off = 32; off; off >>= 1) {
        s  += __shfl_down(s,  off);
        sq += __shfl_down(sq, off);
    }
    int wid = tid >> 6;
    if ((tid & 63) == 0) { sh.ss[wid] = s; sh.ssq[wid] = sq; }
    __syncthreads();
    if (tid == 0) {
        float S  = sh.ss[0] + sh.ss[1] + sh.ss[2] + sh.ss[3];
        float SQ = sh.ssq[0] + sh.ssq[1] + sh.ssq[2] + sh.ssq[3];
        float m  = S * (1.0f / DMODEL);
        float var = SQ * (1.0f / DMODEL) - m * m;
        sh.m = m;
        sh.rs = rsqrtf(var + 1e-5f);
    }
    __syncthreads();
    float m = sh.m, rs = sh.rs;
#pragma unroll
    for (int j = 0; j < 3; j++) {
        int i = tid + j * 256;
        float r = (v[j] - m) * rs * w[i] + b[i];
        if (OUT_BF) ((ushort*)out)[(size_t)row * DMODEL + i] = f2bf(r);
        else        ((float*)out)[(size_t)row * DMODEL + i] = r;
    }
}

__global__ __launch_bounds__(256) void ln2_kernel(
    const float* __restrict__ x, const float* __restrict__ res,
    const float* __restrict__ w, const float* __restrict__ b,
    float* __restrict__ out)
{
    __shared__ LnSh sh;
    ln_row<false>(blockIdx.x, x, res, w, b, (void*)out, sh);
}

// ---------------------------------------------------------------------------
// Prep: weight transpose/cast with zero-padding + input LN.
// mode 0: dst[n*ldd + k] = src[k*N + n] (transpose); tiles over Kp/32 x Np/32
// mode 1: dst[k*ldd + n] = src[k*N + n] (cast)
// OOB (k>=K or n>=N) writes 0.
// ---------------------------------------------------------------------------
struct TD { const float* src; ushort* dst; int K, N, Kp, Np, ldd, tile0, tkp, mode; };
struct PrepArgs {
    TD d[12];
    int ntc;
    const float *x, *in_nw, *in_nb;
    ushort* xn;
};

__global__ __launch_bounds__(256) void prep_kernel(PrepArgs p)
{
    __shared__ union { float tile[32][33]; LnSh l; } sh;
    int bi = blockIdx.x;
    if (bi < p.ntc) {
        int i = 0;
        while (i < 11 && bi >= p.d[i + 1].tile0) i++;
        TD t = p.d[i];
        int local = bi - t.tile0;
        int tki = local % t.tkp, tn = local / t.tkp;
        int k0 = tki * 32, n0 = tn * 32;
        if (t.mode == 0) {
            int tx = threadIdx.x & 31, ty = threadIdx.x >> 5;
#pragma unroll
            for (int r = ty; r < 32; r += 8) {
                int k = k0 + r, n = n0 + tx;
                sh.tile[r][tx] = (k < t.K && n < t.N) ? t.src[(size_t)k * t.N + n] : 0.f;
            }
            __syncthreads();
#pragma unroll
            for (int r = ty; r < 32; r += 8) {
                int n = n0 + r, k = k0 + tx;
                t.dst[(size_t)n * t.ldd + k] = f2bf(sh.tile[tx][r]);
            }
        } else {
#pragma unroll
            for (int e = threadIdx.x; e < 1024; e += 256) {
                int r = e >> 5, c = e & 31;
                int k = k0 + r, n = n0 + c;
                float v = (k < t.K && n < t.N) ? t.src[(size_t)k * t.N + n] : 0.f;
                t.dst[(size_t)k * t.ldd + n] = f2bf(v);
            }
        }
    } else {
        ln_row<true>(bi - p.ntc, p.x, (const float*)nullptr, p.in_nw, p.in_nb,
                     (void*)p.xn, sh.l);
    }
}

// ---------------------------------------------------------------------------
// Weight-fusion dispatch:
//   WzT = (ip_half @ in_w)^T  [1536 x 768], WoT = (out_w @ op_half)^T [768x768]
//   + folded bias GEMVs (fp32).
// ---------------------------------------------------------------------------
struct WfArgs {
    const ushort *fin, *bin, *opT, *ipc, *fow, *bow;
    ushort *WzF, *WzB, *WoF, *WoB;
    const float *ip_b, *f_in_b, *b_in_b, *f_out_b, *b_out_b, *op_b;
    const float *f_in_w32, *b_in_w32, *op_w32;
    float *bzf, *bzb, *bo;
};

__global__ __launch_bounds__(256) void wfuse_kernel(WfArgs p)
{
    __shared__ GemmShT<128, 64> sh;
    int t = blockIdx.x;
    if (t < 432) {
        const ushort *A, *Bt; ushort* C; int lda, ldb, m0, n0;
        if (t < 144)      { A = p.fin;       lda = 384; Bt = p.ipc;       ldb = 768; C = p.WzF; int u = t;       m0 = (u / 12) * 128; n0 = (u % 12) * 64; }
        else if (t < 288) { A = p.bin;       lda = 384; Bt = p.ipc + 384; ldb = 768; C = p.WzB; int u = t - 144; m0 = (u / 12) * 128; n0 = (u % 12) * 64; }
        else if (t < 360) { A = p.opT;       lda = 768; Bt = p.fow;       ldb = 384; C = p.WoF; int u = t - 288; m0 = (u / 12) * 128; n0 = (u % 12) * 64; }
        else              { A = p.opT + 384; lda = 768; Bt = p.bow;       ldb = 384; C = p.WoB; int u = t - 360; m0 = (u / 12) * 128; n0 = (u % 12) * 64; }
        floatx4 acc[4][2];
#pragma unroll
        for (int i = 0; i < 4; i++)
#pragma unroll
            for (int j = 0; j < 2; j++)
                acc[i][j] = (floatx4){0.f, 0.f, 0.f, 0.f};
        gemm_accum<128, 64>(A, lda, Bt, ldb, 384, m0, n0, sh, acc);
        gemm_epilogue<128, 64, true>((const float*)nullptr, (void*)C, 768, 768, m0, n0, acc);
    } else if (t < 438) {          // bz_f (1536 outputs)
        int n = (t - 432) * 256 + threadIdx.x;
        float acc = p.f_in_b[n];
        for (int j = 0; j < 384; j++)
            acc = fmaf(p.ip_b[j], p.f_in_w32[(size_t)j * 1536 + n], acc);
        p.bzf[n] = acc;
    } else if (t < 444) {          // bz_b
        int n = (t - 438) * 256 + threadIdx.x;
        float acc = p.b_in_b[n];
        for (int j = 0; j < 384; j++)
            acc = fmaf(p.ip_b[384 + j], p.b_in_w32[(size_t)j * 1536 + n], acc);
        p.bzb[n] = acc;
    } else {                        // bo (768 outputs)
        int n = (t - 444) * 256 + threadIdx.x;
        float acc = p.op_b[n];
        for (int j = 0; j < 384; j++)
            acc = fmaf(p.f_out_b[j], p.op_w32[(size_t)j * 768 + n], acc);
        for (int j = 0; j < 384; j++)
            acc = fmaf(p.b_out_b[j], p.op_w32[(size_t)(384 + j) * 768 + n], acc);
        p.bo[n] = acc;
    }
}

// ---------------------------------------------------------------------------
// Causal conv1d (K=4) + SiLU, one element/thread, float4 cw.
// ---------------------------------------------------------------------------
__global__ __launch_bounds__(256) void conv_silu_kernel(
    const ushort* __restrict__ xzf, const ushort* __restrict__ xzb,
    const float* __restrict__ cwf, const float* __restrict__ cbf,
    const float* __restrict__ cwb, const float* __restrict__ cbb,
    ushort* __restrict__ outf, ushort* __restrict__ outb)
{
    int rev = blockIdx.y;
    const ushort* xz = rev ? xzb : xzf;
    const float* cw = rev ? cwb : cwf;
    const float* cb = rev ? cbb : cbf;
    ushort* out = rev ? outb : outf;

    int idx = blockIdx.x * 256 + threadIdx.x;
    int d = idx % DINNER;
    int row = idx / DINNER;
    int t = row & (SEQ - 1), b = row >> 11;
    float4 w4 = *(const float4*)&cw[d * 4];
    float wk[4] = {w4.x, w4.y, w4.z, w4.w};
    float acc = cb[d];
#pragma unroll
    for (int k = 0; k < 4; k++) {
        int ts = rev ? (t + 3 - k) : (t - 3 + k);
        if (ts >= 0 && ts < SEQ)
            acc = fmaf(wk[k], bf2f(xz[((size_t)(b * SEQ + ts)) * 1536 + d]), acc);
    }
    float sig = 1.f / (1.f + __expf(-acc));
    out[idx] = f2bf(acc * sig);
}

// ---------------------------------------------------------------------------
// Chunked selective scan (NCH=64, CLEN=32). B/C now read from bf16 xd64
// (cols 24..39 = B, 40..55 = C), wave-uniform 16B loads + convert.
// ---------------------------------------------------------------------------
template<bool FULL>
__global__ __launch_bounds__(256) void scan_chunk_kernel(
    const float* __restrict__ dtf, const ushort* __restrict__ xcf,
    const ushort* __restrict__ xdf, const ushort* __restrict__ xzf,
    const float* __restrict__ Alf, const float* __restrict__ Dff,
    const float* __restrict__ dtb, const ushort* __restrict__ xcb,
    const ushort* __restrict__ xdb, const ushort* __restrict__ xzb,
    const float* __restrict__ Alb, const float* __restrict__ Dbb,
    float* __restrict__ Hloc, float* __restrict__ Wp,
    const float* __restrict__ Hin,
    ushort* __restrict__ yf, ushort* __restrict__ yb)
{
    const int d     = blockIdx.x * 256 + threadIdx.x;
    const int chunk = blockIdx.y;
    const int bz    = blockIdx.z;
    const int dir   = bz >> 1;
    const int bat   = bz & 1;

    const float*  dt = dir ? dtb : dtf;
    const ushort* xc = dir ? xcb : xcf;
    const ushort* xd = dir ? xdb : xdf;
    const ushort* xz = dir ? xzb : xzf;
    const float*  Al = dir ? Alb : Alf;
    const float*  Dp = dir ? Dbb : Dff;
    ushort* yo = dir ? yb : yf;

    float a[16];
    {
        const float4* Ap = (const float4*)(Al + (size_t)d * 16);
#pragma unroll
        for (int q = 0; q < 4; q++) {
            float4 v = Ap[q];
            a[q*4+0] = -__expf(v.x); a[q*4+1] = -__expf(v.y);
            a[q*4+2] = -__expf(v.z); a[q*4+3] = -__expf(v.w);
        }
    }
    const float a0 = a[0];
    bool fast = true;
#pragma unroll
    for (int n = 0; n < 16; n++) {
        float ideal = a0 * (float)(n + 1);
        fast = fast && (fabsf(a[n] - ideal) <= 1e-4f * fabsf(ideal) + 1e-7f);
    }

    float h[16];
    if (FULL) {
        size_t base = ((size_t)(bz * NCH + chunk) * DINNER + d) * 16;
#pragma unroll
        for (int q = 0; q < 4; q++) {
            float4 v = *(const float4*)(Hin + base + q * 4);
            h[q*4+0] = v.x; h[q*4+1] = v.y; h[q*4+2] = v.z; h[q*4+3] = v.w;
        }
    } else {
#pragma unroll
        for (int n = 0; n < 16; n++) h[n] = 0.f;
    }

    const float Dd = FULL ? Dp[d] : 0.f;
    float S = 0.f;

    auto run = [&](auto FASTC) {
        constexpr bool FAST = decltype(FASTC)::value;
#pragma unroll 2
        for (int i = 0; i < CLEN; i++) {
            int tl = chunk * CLEN + i;
            int t  = dir ? (SEQ - 1 - tl) : tl;
            size_t r = (size_t)(bat * SEQ + t);
            float dtv = dt[r * DINNER + d];
            float xv  = bf2f(xc[r * DINNER + d]);
            const ushort* bp = xd + r * 64 + DTRANK;   // wave-uniform
            short8 b0 = *(const short8*)(bp);
            short8 b1 = *(const short8*)(bp + 8);
            float Bv[16];
#pragma unroll
            for (int n = 0; n < 8; n++) {
                Bv[n]     = bf2f((ushort)b0[n]);
                Bv[8 + n] = bf2f((ushort)b1[n]);
            }
            float w[16];
            if (FAST) {
                float e1 = __expf(dtv * a0);
                float e2 = e1*e1, e4 = e2*e2, e8 = e4*e4;
                w[0]=e1;      w[1]=e2;      w[2]=e2*e1;   w[3]=e4;
                w[4]=e4*e1;   w[5]=e4*e2;   w[6]=e4*w[2]; w[7]=e8;
                w[8]=e8*e1;   w[9]=e8*e2;   w[10]=e8*w[2];w[11]=e8*e4;
                w[12]=e8*w[4];w[13]=e8*w[5];w[14]=e8*w[6];w[15]=e8*e8;
            } else {
#pragma unroll
                for (int n = 0; n < 16; n++) w[n] = __expf(dtv * a[n]);
            }
            float bx = dtv * xv;
#pragma unroll
            for (int n = 0; n < 16; n++)
                h[n] = fmaf(w[n], h[n], bx * Bv[n]);
            S += dtv;
            if (FULL) {
                short8 c0 = *(const short8*)(bp + 16);
                short8 c1 = *(const short8*)(bp + 24);
                float Cv[16];
#pragma unroll
                for (int n = 0; n < 8; n++) {
                    Cv[n]     = bf2f((ushort)c0[n]);
                    Cv[8 + n] = bf2f((ushort)c1[n]);
                }
                float y = 0.f;
#pragma unroll
                for (int n = 0; n < 16; n++) y = fmaf(h[n], Cv[n], y);
                float zv = bf2f(xz[r * 1536 + DINNER + d]);
                float sig = 1.f / (1.f + __expf(-zv));
                yo[r * DINNER + d] = f2bf((y + xv * Dd) * (zv * sig));
            }
        }
    };
    if (fast) run(std::true_type{}); else run(std::false_type{});

    if (!FULL) {
        float W[16];
        if (fast) {
            float E1 = __expf(S * a0);
            float E2 = E1*E1, E4 = E2*E2, E8 = E4*E4;
            W[0]=E1;      W[1]=E2;      W[2]=E2*E1;   W[3]=E4;
            W[4]=E4*E1;   W[5]=E4*E2;   W[6]=E4*W[2]; W[7]=E8;
            W[8]=E8*E1;   W[9]=E8*E2;   W[10]=E8*W[2];W[11]=E8*E4;
            W[12]=E8*W[4];W[13]=E8*W[5];W[14]=E8*W[6];W[15]=E8*E8;
        } else {
#pragma unroll
            for (int n = 0; n < 16; n++) W[n] = __expf(S * a[n]);
        }
        size_t base = ((size_t)(bz * NCH + chunk) * DINNER + d) * 16;
#pragma unroll
        for (int q = 0; q < 4; q++) {
            *(float4*)(Hloc + base + q*4) = make_float4(h[q*4+0], h[q*4+1], h[q*4+2], h[q*4+3]);
            *(float4*)(Wp   + base + q*4) = make_float4(W[q*4+0], W[q*4+1], W[q*4+2], W[q*4+3]);
        }
    }
}

__global__ __launch_bounds__(256) void scan_combine(
    const float* __restrict__ Hloc, const float* __restrict__ Wp,
    float* __restrict__ Hin)
{
    int idx = blockIdx.x * 256 + threadIdx.x;
    int bz = idx / (DINNER * 16);
    int rest = idx % (DINNER * 16);
    float hin = 0.f;
#pragma unroll 4
    for (int k = 0; k < NCH; k++) {
        size_t o = (size_t)(bz * NCH + k) * (DINNER * 16) + rest;
        Hin[o] = hin;
        hin = fmaf(Wp[o], hin, Hloc[o]);
    }
}

// ---------------------------------------------------------------------------
extern "C" void kernel_launch(void* const* d_in, const int* in_sizes, int n_in,
                              void* d_out, int out_size, void* d_ws, size_t ws_size,
                              hipStream_t stream)
{
    const float* x        = (const float*)d_in[0];
    const float* in_nw    = (const float*)d_in[1];
    const float* in_nb    = (const float*)d_in[2];
    const float* ip_w     = (const float*)d_in[3];
    const float* ip_b     = (const float*)d_in[4];
    const float* f_in_w   = (const float*)d_in[5];
    const float* f_in_b   = (const float*)d_in[6];
    const float* f_conv_w = (const float*)d_in[7];
    const float* f_conv_b = (const float*)d_in[8];
    const float* f_xp_w   = (const float*)d_in[9];
    const float* f_dt_w   = (const float*)d_in[10];
    const float* f_dt_b   = (const float*)d_in[11];
    const float* f_A_log  = (const float*)d_in[12];
    const float* f_D      = (const float*)d_in[13];
    const float* f_out_w  = (const float*)d_in[14];
    const float* f_out_b  = (const float*)d_in[15];
    const float* b_in_w   = (const float*)d_in[16];
    const float* b_in_b   = (const float*)d_in[17];
    const float* b_conv_w = (const float*)d_in[18];
    const float* b_conv_b = (const float*)d_in[19];
    const float* b_xp_w   = (const float*)d_in[20];
    const float* b_dt_w   = (const float*)d_in[21];
    const float* b_dt_b   = (const float*)d_in[22];
    const float* b_A_log  = (const float*)d_in[23];
    const float* b_D      = (const float*)d_in[24];
    const float* b_out_w  = (const float*)d_in[25];
    const float* b_out_b  = (const float*)d_in[26];
    const float* op_w     = (const float*)d_in[27];
    const float* op_b     = (const float*)d_in[28];
    const float* norm_w   = (const float*)d_in[29];
    const float* norm_b   = (const float*)d_in[30];

    size_t off = 0;
    auto alloc = [&](size_t bytes) {
        void* p = (char*)d_ws + off;
        off += (bytes + 255) & ~(size_t)255;
        return p;
    };
    const size_t R = ROWS;
    ushort* xn_bf   = (ushort*)alloc(R * 768 * 2);
    ushort* xz_f_bf = (ushort*)alloc(R * 1536 * 2);
    ushort* xz_b_bf = (ushort*)alloc(R * 1536 * 2);
    ushort* xc_f_bf = (ushort*)alloc(R * 768 * 2);
    ushort* xc_b_bf = (ushort*)alloc(R * 768 * 2);
    ushort* xd64_f  = (ushort*)alloc(R * 64 * 2);
    ushort* xd64_b  = (ushort*)alloc(R * 64 * 2);
    float*  dt_f    = (float*)alloc(R * 768 * 4);
    float*  dt_b    = (float*)alloc(R * 768 * 4);
    ushort* y_f_bf  = (ushort*)alloc(R * 768 * 2);
    ushort* y_b_bf  = (ushort*)alloc(R * 768 * 2);
    float*  outraw  = (float*)alloc(R * 768 * 4);
    const size_t SCN = (size_t)4 * NCH * DINNER * 16;
    float* Hloc = (float*)alloc(SCN * 4);
    float* Wpb  = (float*)alloc(SCN * 4);
    float* Hin  = (float*)alloc(SCN * 4);
    ushort* Wt_fin = (ushort*)alloc((size_t)1536 * 384 * 2);
    ushort* Wt_bin = (ushort*)alloc((size_t)1536 * 384 * 2);
    ushort* Wt_op  = (ushort*)alloc((size_t)768 * 768 * 2);
    ushort* Wt_fxp = (ushort*)alloc((size_t)64 * 768 * 2);
    ushort* Wt_bxp = (ushort*)alloc((size_t)64 * 768 * 2);
    ushort* dtwT_f = (ushort*)alloc((size_t)768 * 64 * 2);
    ushort* dtwT_b = (ushort*)alloc((size_t)768 * 64 * 2);
    ushort* ipc    = (ushort*)alloc((size_t)768 * 768 * 2);
    ushort* fow    = (ushort*)alloc((size_t)768 * 384 * 2);
    ushort* bow    = (ushort*)alloc((size_t)768 * 384 * 2);
    ushort* WzF    = (ushort*)alloc((size_t)1536 * 768 * 2);
    ushort* WzB    = (ushort*)alloc((size_t)1536 * 768 * 2);
    ushort* WoF    = (ushort*)alloc((size_t)768 * 768 * 2);
    ushort* WoB    = (ushort*)alloc((size_t)768 * 768 * 2);
    float*  bzf    = (float*)alloc(1536 * 4);
    float*  bzb    = (float*)alloc(1536 * 4);
    float*  bo     = (float*)alloc(768 * 4);

    // ---- D1: prep (tcast + ln1) ----
    PrepArgs pa;
    int tile0 = 0, nd = 0;
    auto add = [&](const float* s, ushort* dst, int K, int N, int Kp, int Np,
                   int ldd, int mode) {
        pa.d[nd] = TD{s, dst, K, N, Kp, Np, ldd, tile0, Kp / 32, mode};
        tile0 += (Kp / 32) * (Np / 32);
        nd++;
    };
    add(f_in_w,  Wt_fin, 384, 1536, 384, 1536, 384, 0);
    add(b_in_w,  Wt_bin, 384, 1536, 384, 1536, 384, 0);
    add(op_w,    Wt_op,  768, 768,  768, 768,  768, 0);
    add(f_xp_w,  Wt_fxp, 768, 56,   768, 64,   768, 0);
    add(b_xp_w,  Wt_bxp, 768, 56,   768, 64,   768, 0);
    add(f_dt_w,  dtwT_f, 24,  768,  64,  768,  64,  0);  // zero-padded K 24->64
    add(b_dt_w,  dtwT_b, 24,  768,  64,  768,  64,  0);
    add(ip_w,    ipc,    768, 768,  768, 768,  768, 1);
    add(f_out_w, fow,    768, 384,  768, 384,  384, 1);
    add(b_out_w, bow,    768, 384,  768, 384,  384, 1);
    pa.ntc = tile0;
    for (int i = nd; i < 12; i++) pa.d[i].tile0 = 0x7fffffff;
    pa.x = x; pa.in_nw = in_nw; pa.in_nb = in_nb; pa.xn = xn_bf;
    hipLaunchKernelGGL(prep_kernel, dim3(tile0 + ROWS), dim3(256), 0, stream, pa);

    // ---- D2: weight fusion ----
    WfArgs wa;
    wa.fin = Wt_fin; wa.bin = Wt_bin; wa.opT = Wt_op;
    wa.ipc = ipc; wa.fow = fow; wa.bow = bow;
    wa.WzF = WzF; wa.WzB = WzB; wa.WoF = WoF; wa.WoB = WoB;
    wa.ip_b = ip_b; wa.f_in_b = f_in_b; wa.b_in_b = b_in_b;
    wa.f_out_b = f_out_b; wa.b_out_b = b_out_b; wa.op_b = op_b;
    wa.f_in_w32 = f_in_w; wa.b_in_w32 = b_in_w; wa.op_w32 = op_w;
    wa.bzf = bzf; wa.bzb = bzb; wa.bo = bo;
    hipLaunchKernelGGL(wfuse_kernel, dim3(447), dim3(256), 0, stream, wa);

    // ---- D3: xz_{f,b} = xn @ Wz + bz (K=768, ip folded in) ----
    hipLaunchKernelGGL((mfma_gemm_k<128, 128, true>), dim3(12, 32, 2), dim3(256), 0, stream,
                       xn_bf, xn_bf, 768, WzF, WzB, 768, bzf, bzb,
                       (void*)xz_f_bf, (void*)xz_b_bf, 1536, 1536, 768);

    // ---- D4: conv + silu ----
    hipLaunchKernelGGL(conv_silu_kernel, dim3(ROWS * DINNER / 256, 2), dim3(256), 0, stream,
                       xz_f_bf, xz_b_bf, f_conv_w, f_conv_b, b_conv_w, b_conv_b,
                       xc_f_bf, xc_b_bf);

    // ---- D5: xd64 = xc @ xp_w (bf16 out, cols 0..23 dt-rank, 24..55 B/C) ----
    hipLaunchKernelGGL((mfma_gemm_k<64, 64, true>), dim3(1, 64, 2), dim3(256), 0, stream,
                       xc_f_bf, xc_b_bf, 768, Wt_fxp, Wt_bxp, 768,
                       (const float*)nullptr, (const float*)nullptr,
                       (void*)xd64_f, (void*)xd64_b, 64, 64, 768);

    // ---- D6: dt = softplus(xd64 @ dtwT + dt_b), K=64, fast softplus ----
    hipLaunchKernelGGL(dt_kernel, dim3(12, 32, 2), dim3(256), 0, stream,
                       xd64_f, xd64_b, dtwT_f, dtwT_b, f_dt_b, b_dt_b, dt_f, dt_b);

    // ---- D7/D8/D9: chunked selective scan ----
    hipLaunchKernelGGL((scan_chunk_kernel<false>), dim3(DINNER / 256, NCH, 4), dim3(256), 0, stream,
                       dt_f, xc_f_bf, xd64_f, xz_f_bf, f_A_log, f_D,
                       dt_b, xc_b_bf, xd64_b, xz_b_bf, b_A_log, b_D,
                       Hloc, Wpb, (const float*)nullptr, (ushort*)nullptr, (ushort*)nullptr);
    hipLaunchKernelGGL(scan_combine, dim3(4 * DINNER * 16 / 256), dim3(256), 0, stream,
                       Hloc, Wpb, Hin);
    hipLaunchKernelGGL((scan_chunk_kernel<true>), dim3(DINNER / 256, NCH, 4), dim3(256), 0, stream,
                       dt_f, xc_f_bf, xd64_f, xz_f_bf, f_A_log, f_D,
                       dt_b, xc_b_bf, xd64_b, xz_b_bf, b_A_log, b_D,
                       (float*)nullptr, (float*)nullptr, Hin, y_f_bf, y_b_bf);

    // ---- D10: outraw = y_f @ WoF + y_b @ WoB + bo ----
    hipLaunchKernelGGL((outop_kernel<128, 64>), dim3(12, 32), dim3(256), 0, stream,
                       y_f_bf, WoF, y_b_bf, WoB, bo, outraw, 768, 768, 768, 768, 768);

    // ---- D11: final layernorm(residual + out) ----
    hipLaunchKernelGGL(ln2_kernel, dim3(ROWS), dim3(256), 0, stream,
                       x, outraw, norm_w, norm_b, (float*)d_out);
}

// Round 9
// 324.101 us; speedup vs baseline: 7.9897x; 1.0228x over previous
//
#include <hip/hip_runtime.h>
#include <hip/hip_bf16.h>
#include <math.h>
#include <type_traits>

#define BATCH 2
#define SEQ   2048
#define DMODEL 768
#define DIN   384
#define DINNER 768
#define DSTATE 16
#define DTRANK 24
#define ROWS  (BATCH*SEQ)   // 4096
#define NCH   64            // time chunks for the scan
#define CLEN  (SEQ/NCH)     // 32 steps per chunk

using short8  = __attribute__((ext_vector_type(8))) short;
using floatx4 = __attribute__((ext_vector_type(4))) float;

__device__ __forceinline__ ushort f2bf(float f) {
    union { float f; uint u; } v; v.f = f;
    uint r = (v.u + 0x7fffu + ((v.u >> 16) & 1u)) >> 16;
    return (ushort)r;
}
__device__ __forceinline__ float bf2f(ushort h) {
    union { uint u; float f; } v; v.u = ((uint)h) << 16;
    return v.f;
}
__device__ __forceinline__ void async16(const ushort* g, ushort* l) {
    __builtin_amdgcn_global_load_lds(
        (const __attribute__((address_space(1))) void*)g,
        (__attribute__((address_space(3))) void*)l,
        16, 0, 0);
}
// softplus via fast HW transcendentals (v_exp_f32 + v_log_f32), not log1pf
__device__ __forceinline__ float softplus_fast(float v) {
    if (v > 20.f) return v;
    float e = __expf(-fabsf(v));
    return fmaxf(v, 0.f) + __logf(1.f + e);
}

// ---------------------------------------------------------------------------
// MFMA GEMM building blocks (m97 staging, BK=64, XOR-swizzled LDS).
// [R7: conflicts 7.1M -> 0]
// ---------------------------------------------------------------------------
template<int TM, int TN> struct GemmShT { ushort lA[TM * 64]; ushort lB[TN * 64]; };

template<int TM, int TN>
__device__ __forceinline__ void gemm_accum(
    const ushort* __restrict__ A, int lda,
    const ushort* __restrict__ Bt, int ldb,
    int K, int m0, int n0, GemmShT<TM, TN>& sh,
    floatx4 (&acc)[TM / 32][TN / 32])
{
    constexpr int WM = TM / 2, WN = TN / 2;
    constexpr int MT = WM / 16, NT = WN / 16;
    constexpr int AI = TM / 32, BI = TN / 32;
    const int tid = threadIdx.x;
    const int wave = tid >> 6, lane = tid & 63;
    const int wm = wave >> 1, wn = wave & 1;
    const int quad = lane >> 4, l16 = lane & 15;
    const int lrow = lane >> 3;                      // 8 rows per 1KB wave-store
    const int lcol = ((lane & 7) ^ (lane >> 3)) * 8; // XOR-swizzled source granule

    for (int k0 = 0; k0 < K; k0 += 64) {
#pragma unroll
        for (int i = 0; i < AI; i++) {
            int rb = (wave * AI + i) * 8;
            async16(A + (size_t)(m0 + rb + lrow) * lda + k0 + lcol, &sh.lA[rb * 64]);
        }
#pragma unroll
        for (int i = 0; i < BI; i++) {
            int rb = (wave * BI + i) * 8;
            async16(Bt + (size_t)(n0 + rb + lrow) * ldb + k0 + lcol, &sh.lB[rb * 64]);
        }
        __syncthreads();
#pragma unroll
        for (int ks = 0; ks < 2; ks++) {
            short8 af[MT], bf[NT];
#pragma unroll
            for (int i = 0; i < MT; i++) {
                int row = wm * WM + i * 16 + l16;
                af[i] = *(const short8*)&sh.lA[row * 64 + ((ks * 4 + quad) ^ (row & 7)) * 8];
            }
#pragma unroll
            for (int j = 0; j < NT; j++) {
                int row = wn * WN + j * 16 + l16;
                bf[j] = *(const short8*)&sh.lB[row * 64 + ((ks * 4 + quad) ^ (row & 7)) * 8];
            }
#pragma unroll
            for (int i = 0; i < MT; i++)
#pragma unroll
                for (int j = 0; j < NT; j++)
                    acc[i][j] = __builtin_amdgcn_mfma_f32_16x16x32_bf16(af[i], bf[j], acc[i][j], 0, 0, 0);
        }
        __syncthreads();
    }
}

template<int TM, int TN, bool OUT_BF>
__device__ __forceinline__ void gemm_epilogue(
    const float* __restrict__ bias, void* __restrict__ C, int ldc, int N,
    int m0, int n0, floatx4 (&acc)[TM / 32][TN / 32])
{
    constexpr int WM = TM / 2, WN = TN / 2;
    constexpr int MT = WM / 16, NT = WN / 16;
    const int tid = threadIdx.x;
    const int wave = tid >> 6, lane = tid & 63;
    const int wm = wave >> 1, wn = wave & 1;
    const int quad = lane >> 4, l16 = lane & 15;
#pragma unroll
    for (int i = 0; i < MT; i++) {
#pragma unroll
        for (int j = 0; j < NT; j++) {
            int row = m0 + wm * WM + i * 16 + quad * 4;
            int col = n0 + wn * WN + j * 16 + l16;
            if (col < N) {
                float bv = bias ? bias[col] : 0.f;
#pragma unroll
                for (int r = 0; r < 4; r++) {
                    float v = acc[i][j][r] + bv;
                    if (OUT_BF) ((ushort*)C)[(size_t)(row + r) * ldc + col] = f2bf(v);
                    else        ((float*)C)[(size_t)(row + r) * ldc + col] = v;
                }
            }
        }
    }
}

// Generic single-pair GEMM kernel; grid.z selects f/b operand sets.
template<int TM, int TN, bool OUT_BF>
__global__ __launch_bounds__(256) void mfma_gemm_k(
    const ushort* __restrict__ A0, const ushort* __restrict__ A1, int lda,
    const ushort* __restrict__ B0, const ushort* __restrict__ B1, int ldb,
    const float* __restrict__ bias0, const float* __restrict__ bias1,
    void* __restrict__ C0, void* __restrict__ C1, int ldc, int N, int K)
{
    __shared__ GemmShT<TM, TN> sh;
    const ushort* A  = blockIdx.z ? A1 : A0;
    const ushort* Bt = blockIdx.z ? B1 : B0;
    const float* bias = blockIdx.z ? bias1 : bias0;
    void* C = blockIdx.z ? C1 : C0;
    floatx4 acc[TM / 32][TN / 32];
#pragma unroll
    for (int i = 0; i < TM / 32; i++)
#pragma unroll
        for (int j = 0; j < TN / 32; j++)
            acc[i][j] = (floatx4){0.f, 0.f, 0.f, 0.f};
    int m0 = blockIdx.y * TM, n0 = blockIdx.x * TN;
    gemm_accum<TM, TN>(A, lda, Bt, ldb, K, m0, n0, sh, acc);
    gemm_epilogue<TM, TN, OUT_BF>(bias, C, ldc, N, m0, n0, acc);
}

// dt = softplus(xd64 @ dtwT^T + dt_b). K=64 (zero-padded rows annihilate
// the B/C columns). Fast-softplus epilogue, bf16 out.
__global__ __launch_bounds__(256) void dt_kernel(
    const ushort* __restrict__ xdf, const ushort* __restrict__ xdb,
    const ushort* __restrict__ dtwTf, const ushort* __restrict__ dtwTb,
    const float* __restrict__ dtbf, const float* __restrict__ dtbb,
    ushort* __restrict__ dtf, ushort* __restrict__ dtb)
{
    constexpr int TM = 128, TN = 64;
    __shared__ GemmShT<TM, TN> sh;
    const ushort* A  = blockIdx.z ? xdb : xdf;
    const ushort* Bt = blockIdx.z ? dtwTb : dtwTf;
    const float* bias = blockIdx.z ? dtbb : dtbf;
    ushort* C = blockIdx.z ? dtb : dtf;
    floatx4 acc[4][2];
#pragma unroll
    for (int i = 0; i < 4; i++)
#pragma unroll
        for (int j = 0; j < 2; j++)
            acc[i][j] = (floatx4){0.f, 0.f, 0.f, 0.f};
    int m0 = blockIdx.y * TM, n0 = blockIdx.x * TN;
    gemm_accum<TM, TN>(A, 64, Bt, 64, 64, m0, n0, sh, acc);
    const int tid = threadIdx.x;
    const int wave = tid >> 6, lane = tid & 63;
    const int wm = wave >> 1, wn = wave & 1;
    const int quad = lane >> 4, l16 = lane & 15;
#pragma unroll
    for (int i = 0; i < 4; i++) {
#pragma unroll
        for (int j = 0; j < 2; j++) {
            int row = m0 + wm * 64 + i * 16 + quad * 4;
            int col = n0 + wn * 32 + j * 16 + l16;
            float bv = bias[col];
#pragma unroll
            for (int r = 0; r < 4; r++)
                C[(size_t)(row + r) * 768 + col] = f2bf(softplus_fast(acc[i][j][r] + bv));
        }
    }
}

// Dual-A GEMM: C = A0@B0^T + A1@B1^T + bias (fused out+op projection).
template<int TM, int TN>
__global__ __launch_bounds__(256) void outop_kernel(
    const ushort* __restrict__ A0, const ushort* __restrict__ B0,
    const ushort* __restrict__ A1, const ushort* __restrict__ B1,
    const float* __restrict__ bias, float* __restrict__ C,
    int lda, int ldb, int ldc, int N, int K)
{
    __shared__ GemmShT<TM, TN> sh;
    floatx4 acc[TM / 32][TN / 32];
#pragma unroll
    for (int i = 0; i < TM / 32; i++)
#pragma unroll
        for (int j = 0; j < TN / 32; j++)
            acc[i][j] = (floatx4){0.f, 0.f, 0.f, 0.f};
    int m0 = blockIdx.y * TM, n0 = blockIdx.x * TN;
    gemm_accum<TM, TN>(A0, lda, B0, ldb, K, m0, n0, sh, acc);
    gemm_accum<TM, TN>(A1, lda, B1, ldb, K, m0, n0, sh, acc);
    gemm_epilogue<TM, TN, false>(bias, (void*)C, ldc, N, m0, n0, acc);
}

// ---------------------------------------------------------------------------
// LayerNorm row helper (+ standalone kernel for the final LN).
// ---------------------------------------------------------------------------
struct LnSh { float ss[4]; float ssq[4]; float m; float rs; };

template<bool OUT_BF>
__device__ __forceinline__ void ln_row(
    int row, const float* __restrict__ x, const float* __restrict__ res,
    const float* __restrict__ w, const float* __restrict__ b,
    void* __restrict__ out, LnSh& sh)
{
    int tid = threadIdx.x;
    const float* xr = x + (size_t)row * DMODEL;
    const float* rr = res ? res + (size_t)row * DMODEL : nullptr;
    float v[3];
    float s = 0.f, sq = 0.f;
#pragma unroll
    for (int j = 0; j < 3; j++) {
        int i = tid + j * 256;
        float val = xr[i];
        if (rr) val += rr[i];
        v[j] = val; s += val; sq += val * val;
    }
#pragma unroll
    for (int off = 32; off; off >>= 1) {
        s  += __shfl_down(s,  off);
        sq += __shfl_down(sq, off);
    }
    int wid = tid >> 6;
    if ((tid & 63) == 0) { sh.ss[wid] = s; sh.ssq[wid] = sq; }
    __syncthreads();
    if (tid == 0) {
        float S  = sh.ss[0] + sh.ss[1] + sh.ss[2] + sh.ss[3];
        float SQ = sh.ssq[0] + sh.ssq[1] + sh.ssq[2] + sh.ssq[3];
        float m  = S * (1.0f / DMODEL);
        float var = SQ * (1.0f / DMODEL) - m * m;
        sh.m = m;
        sh.rs = rsqrtf(var + 1e-5f);
    }
    __syncthreads();
    float m = sh.m, rs = sh.rs;
#pragma unroll
    for (int j = 0; j < 3; j++) {
        int i = tid + j * 256;
        float r = (v[j] - m) * rs * w[i] + b[i];
        if (OUT_BF) ((ushort*)out)[(size_t)row * DMODEL + i] = f2bf(r);
        else        ((float*)out)[(size_t)row * DMODEL + i] = r;
    }
}

__global__ __launch_bounds__(256) void ln2_kernel(
    const float* __restrict__ x, const float* __restrict__ res,
    const float* __restrict__ w, const float* __restrict__ b,
    float* __restrict__ out)
{
    __shared__ LnSh sh;
    ln_row<false>(blockIdx.x, x, res, w, b, (void*)out, sh);
}

// ---------------------------------------------------------------------------
// Prep: weight transpose/cast with zero-padding + input LN.
// ---------------------------------------------------------------------------
struct TD { const float* src; ushort* dst; int K, N, Kp, Np, ldd, tile0, tkp, mode; };
struct PrepArgs {
    TD d[12];
    int ntc;
    const float *x, *in_nw, *in_nb;
    ushort* xn;
};

__global__ __launch_bounds__(256) void prep_kernel(PrepArgs p)
{
    __shared__ union { float tile[32][33]; LnSh l; } sh;
    int bi = blockIdx.x;
    if (bi < p.ntc) {
        int i = 0;
        while (i < 11 && bi >= p.d[i + 1].tile0) i++;
        TD t = p.d[i];
        int local = bi - t.tile0;
        int tki = local % t.tkp, tn = local / t.tkp;
        int k0 = tki * 32, n0 = tn * 32;
        if (t.mode == 0) {
            int tx = threadIdx.x & 31, ty = threadIdx.x >> 5;
#pragma unroll
            for (int r = ty; r < 32; r += 8) {
                int k = k0 + r, n = n0 + tx;
                sh.tile[r][tx] = (k < t.K && n < t.N) ? t.src[(size_t)k * t.N + n] : 0.f;
            }
            __syncthreads();
#pragma unroll
            for (int r = ty; r < 32; r += 8) {
                int n = n0 + r, k = k0 + tx;
                t.dst[(size_t)n * t.ldd + k] = f2bf(sh.tile[tx][r]);
            }
        } else {
#pragma unroll
            for (int e = threadIdx.x; e < 1024; e += 256) {
                int r = e >> 5, c = e & 31;
                int k = k0 + r, n = n0 + c;
                float v = (k < t.K && n < t.N) ? t.src[(size_t)k * t.N + n] : 0.f;
                t.dst[(size_t)k * t.ldd + n] = f2bf(v);
            }
        }
    } else {
        ln_row<true>(bi - p.ntc, p.x, (const float*)nullptr, p.in_nw, p.in_nb,
                     (void*)p.xn, sh.l);
    }
}

// ---------------------------------------------------------------------------
// Weight-fusion dispatch. GEMV blocks FIRST (ids 0..14, they are the long
// pole) then the 432 GEMM tiles. GEMV j-loops unrolled x16 so 16 loads are
// in flight (R8: un-annotated loop serialized at ~225 cyc/load = 36 us).
// ---------------------------------------------------------------------------
struct WfArgs {
    const ushort *fin, *bin, *opT, *ipc, *fow, *bow;
    ushort *WzF, *WzB, *WoF, *WoB;
    const float *ip_b, *f_in_b, *b_in_b, *f_out_b, *b_out_b, *op_b;
    const float *f_in_w32, *b_in_w32, *op_w32;
    float *bzf, *bzb, *bo;
};

__global__ __launch_bounds__(256) void wfuse_kernel(WfArgs p)
{
    __shared__ GemmShT<128, 64> sh;
    int t = blockIdx.x;
    if (t < 6) {                   // bz_f (1536 outputs)
        int n = t * 256 + threadIdx.x;
        float acc = p.f_in_b[n];
#pragma unroll 16
        for (int j = 0; j < 384; j++)
            acc = fmaf(p.ip_b[j], p.f_in_w32[(size_t)j * 1536 + n], acc);
        p.bzf[n] = acc;
    } else if (t < 12) {           // bz_b
        int n = (t - 6) * 256 + threadIdx.x;
        float acc = p.b_in_b[n];
#pragma unroll 16
        for (int j = 0; j < 384; j++)
            acc = fmaf(p.ip_b[384 + j], p.b_in_w32[(size_t)j * 1536 + n], acc);
        p.bzb[n] = acc;
    } else if (t < 15) {           // bo (768 outputs)
        int n = (t - 12) * 256 + threadIdx.x;
        float acc = p.op_b[n];
#pragma unroll 16
        for (int j = 0; j < 384; j++)
            acc = fmaf(p.f_out_b[j], p.op_w32[(size_t)j * 768 + n], acc);
#pragma unroll 16
        for (int j = 0; j < 384; j++)
            acc = fmaf(p.b_out_b[j], p.op_w32[(size_t)(384 + j) * 768 + n], acc);
        p.bo[n] = acc;
    } else {
        int g = t - 15;
        const ushort *A, *Bt; ushort* C; int lda, ldb, m0, n0;
        if (g < 144)      { A = p.fin;       lda = 384; Bt = p.ipc;       ldb = 768; C = p.WzF; int u = g;       m0 = (u / 12) * 128; n0 = (u % 12) * 64; }
        else if (g < 288) { A = p.bin;       lda = 384; Bt = p.ipc + 384; ldb = 768; C = p.WzB; int u = g - 144; m0 = (u / 12) * 128; n0 = (u % 12) * 64; }
        else if (g < 360) { A = p.opT;       lda = 768; Bt = p.fow;       ldb = 384; C = p.WoF; int u = g - 288; m0 = (u / 12) * 128; n0 = (u % 12) * 64; }
        else              { A = p.opT + 384; lda = 768; Bt = p.bow;       ldb = 384; C = p.WoB; int u = g - 360; m0 = (u / 12) * 128; n0 = (u % 12) * 64; }
        floatx4 acc[4][2];
#pragma unroll
        for (int i = 0; i < 4; i++)
#pragma unroll
            for (int j = 0; j < 2; j++)
                acc[i][j] = (floatx4){0.f, 0.f, 0.f, 0.f};
        gemm_accum<128, 64>(A, lda, Bt, ldb, 384, m0, n0, sh, acc);
        gemm_epilogue<128, 64, true>((const float*)nullptr, (void*)C, 768, 768, m0, n0, acc);
    }
}

// ---------------------------------------------------------------------------
// Causal conv1d (K=4) + SiLU, one element/thread, float4 cw.
// ---------------------------------------------------------------------------
__global__ __launch_bounds__(256) void conv_silu_kernel(
    const ushort* __restrict__ xzf, const ushort* __restrict__ xzb,
    const float* __restrict__ cwf, const float* __restrict__ cbf,
    const float* __restrict__ cwb, const float* __restrict__ cbb,
    ushort* __restrict__ outf, ushort* __restrict__ outb)
{
    int rev = blockIdx.y;
    const ushort* xz = rev ? xzb : xzf;
    const float* cw = rev ? cwb : cwf;
    const float* cb = rev ? cbb : cbf;
    ushort* out = rev ? outb : outf;

    int idx = blockIdx.x * 256 + threadIdx.x;
    int d = idx % DINNER;
    int row = idx / DINNER;
    int t = row & (SEQ - 1), b = row >> 11;
    float4 w4 = *(const float4*)&cw[d * 4];
    float wk[4] = {w4.x, w4.y, w4.z, w4.w};
    float acc = cb[d];
#pragma unroll
    for (int k = 0; k < 4; k++) {
        int ts = rev ? (t + 3 - k) : (t - 3 + k);
        if (ts >= 0 && ts < SEQ)
            acc = fmaf(wk[k], bf2f(xz[((size_t)(b * SEQ + ts)) * 1536 + d]), acc);
    }
    float sig = 1.f / (1.f + __expf(-acc));
    out[idx] = f2bf(acc * sig);
}

// ---------------------------------------------------------------------------
// Chunked selective scan (NCH=64, CLEN=32). dt now bf16; B/C from bf16 xd64.
// ---------------------------------------------------------------------------
template<bool FULL>
__global__ __launch_bounds__(256) void scan_chunk_kernel(
    const ushort* __restrict__ dtf, const ushort* __restrict__ xcf,
    const ushort* __restrict__ xdf, const ushort* __restrict__ xzf,
    const float* __restrict__ Alf, const float* __restrict__ Dff,
    const ushort* __restrict__ dtb, const ushort* __restrict__ xcb,
    const ushort* __restrict__ xdb, const ushort* __restrict__ xzb,
    const float* __restrict__ Alb, const float* __restrict__ Dbb,
    float* __restrict__ Hloc, float* __restrict__ Wp,
    const float* __restrict__ Hin,
    ushort* __restrict__ yf, ushort* __restrict__ yb)
{
    const int d     = blockIdx.x * 256 + threadIdx.x;
    const int chunk = blockIdx.y;
    const int bz    = blockIdx.z;
    const int dir   = bz >> 1;
    const int bat   = bz & 1;

    const ushort* dt = dir ? dtb : dtf;
    const ushort* xc = dir ? xcb : xcf;
    const ushort* xd = dir ? xdb : xdf;
    const ushort* xz = dir ? xzb : xzf;
    const float*  Al = dir ? Alb : Alf;
    const float*  Dp = dir ? Dbb : Dff;
    ushort* yo = dir ? yb : yf;

    float a[16];
    {
        const float4* Ap = (const float4*)(Al + (size_t)d * 16);
#pragma unroll
        for (int q = 0; q < 4; q++) {
            float4 v = Ap[q];
            a[q*4+0] = -__expf(v.x); a[q*4+1] = -__expf(v.y);
            a[q*4+2] = -__expf(v.z); a[q*4+3] = -__expf(v.w);
        }
    }
    const float a0 = a[0];
    bool fast = true;
#pragma unroll
    for (int n = 0; n < 16; n++) {
        float ideal = a0 * (float)(n + 1);
        fast = fast && (fabsf(a[n] - ideal) <= 1e-4f * fabsf(ideal) + 1e-7f);
    }

    float h[16];
    if (FULL) {
        size_t base = ((size_t)(bz * NCH + chunk) * DINNER + d) * 16;
#pragma unroll
        for (int q = 0; q < 4; q++) {
            float4 v = *(const float4*)(Hin + base + q * 4);
            h[q*4+0] = v.x; h[q*4+1] = v.y; h[q*4+2] = v.z; h[q*4+3] = v.w;
        }
    } else {
#pragma unroll
        for (int n = 0; n < 16; n++) h[n] = 0.f;
    }

    const float Dd = FULL ? Dp[d] : 0.f;
    float S = 0.f;

    auto run = [&](auto FASTC) {
        constexpr bool FAST = decltype(FASTC)::value;
#pragma unroll 2
        for (int i = 0; i < CLEN; i++) {
            int tl = chunk * CLEN + i;
            int t  = dir ? (SEQ - 1 - tl) : tl;
            size_t r = (size_t)(bat * SEQ + t);
            float dtv = bf2f(dt[r * DINNER + d]);
            float xv  = bf2f(xc[r * DINNER + d]);
            const ushort* bp = xd + r * 64 + DTRANK;   // wave-uniform
            short8 b0 = *(const short8*)(bp);
            short8 b1 = *(const short8*)(bp + 8);
            float Bv[16];
#pragma unroll
            for (int n = 0; n < 8; n++) {
                Bv[n]     = bf2f((ushort)b0[n]);
                Bv[8 + n] = bf2f((ushort)b1[n]);
            }
            float w[16];
            if (FAST) {
                float e1 = __expf(dtv * a0);
                float e2 = e1*e1, e4 = e2*e2, e8 = e4*e4;
                w[0]=e1;      w[1]=e2;      w[2]=e2*e1;   w[3]=e4;
                w[4]=e4*e1;   w[5]=e4*e2;   w[6]=e4*w[2]; w[7]=e8;
                w[8]=e8*e1;   w[9]=e8*e2;   w[10]=e8*w[2];w[11]=e8*e4;
                w[12]=e8*w[4];w[13]=e8*w[5];w[14]=e8*w[6];w[15]=e8*e8;
            } else {
#pragma unroll
                for (int n = 0; n < 16; n++) w[n] = __expf(dtv * a[n]);
            }
            float bx = dtv * xv;
#pragma unroll
            for (int n = 0; n < 16; n++)
                h[n] = fmaf(w[n], h[n], bx * Bv[n]);
            S += dtv;
            if (FULL) {
                short8 c0 = *(const short8*)(bp + 16);
                short8 c1 = *(const short8*)(bp + 24);
                float Cv[16];
#pragma unroll
                for (int n = 0; n < 8; n++) {
                    Cv[n]     = bf2f((ushort)c0[n]);
                    Cv[8 + n] = bf2f((ushort)c1[n]);
                }
                float y = 0.f;
#pragma unroll
                for (int n = 0; n < 16; n++) y = fmaf(h[n], Cv[n], y);
                float zv = bf2f(xz[r * 1536 + DINNER + d]);
                float sig = 1.f / (1.f + __expf(-zv));
                yo[r * DINNER + d] = f2bf((y + xv * Dd) * (zv * sig));
            }
        }
    };
    if (fast) run(std::true_type{}); else run(std::false_type{});

    if (!FULL) {
        float W[16];
        if (fast) {
            float E1 = __expf(S * a0);
            float E2 = E1*E1, E4 = E2*E2, E8 = E4*E4;
            W[0]=E1;      W[1]=E2;      W[2]=E2*E1;   W[3]=E4;
            W[4]=E4*E1;   W[5]=E4*E2;   W[6]=E4*W[2]; W[7]=E8;
            W[8]=E8*E1;   W[9]=E8*E2;   W[10]=E8*W[2];W[11]=E8*E4;
            W[12]=E8*W[4];W[13]=E8*W[5];W[14]=E8*W[6];W[15]=E8*E8;
        } else {
#pragma unroll
            for (int n = 0; n < 16; n++) W[n] = __expf(S * a[n]);
        }
        size_t base = ((size_t)(bz * NCH + chunk) * DINNER + d) * 16;
#pragma unroll
        for (int q = 0; q < 4; q++) {
            *(float4*)(Hloc + base + q*4) = make_float4(h[q*4+0], h[q*4+1], h[q*4+2], h[q*4+3]);
            *(float4*)(Wp   + base + q*4) = make_float4(W[q*4+0], W[q*4+1], W[q*4+2], W[q*4+3]);
        }
    }
}

__global__ __launch_bounds__(256) void scan_combine(
    const float* __restrict__ Hloc, const float* __restrict__ Wp,
    float* __restrict__ Hin)
{
    int idx = blockIdx.x * 256 + threadIdx.x;
    int bz = idx / (DINNER * 16);
    int rest = idx % (DINNER * 16);
    float hin = 0.f;
#pragma unroll 4
    for (int k = 0; k < NCH; k++) {
        size_t o = (size_t)(bz * NCH + k) * (DINNER * 16) + rest;
        Hin[o] = hin;
        hin = fmaf(Wp[o], hin, Hloc[o]);
    }
}

// ---------------------------------------------------------------------------
extern "C" void kernel_launch(void* const* d_in, const int* in_sizes, int n_in,
                              void* d_out, int out_size, void* d_ws, size_t ws_size,
                              hipStream_t stream)
{
    const float* x        = (const float*)d_in[0];
    const float* in_nw    = (const float*)d_in[1];
    const float* in_nb    = (const float*)d_in[2];
    const float* ip_w     = (const float*)d_in[3];
    const float* ip_b     = (const float*)d_in[4];
    const float* f_in_w   = (const float*)d_in[5];
    const float* f_in_b   = (const float*)d_in[6];
    const float* f_conv_w = (const float*)d_in[7];
    const float* f_conv_b = (const float*)d_in[8];
    const float* f_xp_w   = (const float*)d_in[9];
    const float* f_dt_w   = (const float*)d_in[10];
    const float* f_dt_b   = (const float*)d_in[11];
    const float* f_A_log  = (const float*)d_in[12];
    const float* f_D      = (const float*)d_in[13];
    const float* f_out_w  = (const float*)d_in[14];
    const float* f_out_b  = (const float*)d_in[15];
    const float* b_in_w   = (const float*)d_in[16];
    const float* b_in_b   = (const float*)d_in[17];
    const float* b_conv_w = (const float*)d_in[18];
    const float* b_conv_b = (const float*)d_in[19];
    const float* b_xp_w   = (const float*)d_in[20];
    const float* b_dt_w   = (const float*)d_in[21];
    const float* b_dt_b   = (const float*)d_in[22];
    const float* b_A_log  = (const float*)d_in[23];
    const float* b_D      = (const float*)d_in[24];
    const float* b_out_w  = (const float*)d_in[25];
    const float* b_out_b  = (const float*)d_in[26];
    const float* op_w     = (const float*)d_in[27];
    const float* op_b     = (const float*)d_in[28];
    const float* norm_w   = (const float*)d_in[29];
    const float* norm_b   = (const float*)d_in[30];

    size_t off = 0;
    auto alloc = [&](size_t bytes) {
        void* p = (char*)d_ws + off;
        off += (bytes + 255) & ~(size_t)255;
        return p;
    };
    const size_t R = ROWS;
    ushort* xn_bf   = (ushort*)alloc(R * 768 * 2);
    ushort* xz_f_bf = (ushort*)alloc(R * 1536 * 2);
    ushort* xz_b_bf = (ushort*)alloc(R * 1536 * 2);
    ushort* xc_f_bf = (ushort*)alloc(R * 768 * 2);
    ushort* xc_b_bf = (ushort*)alloc(R * 768 * 2);
    ushort* xd64_f  = (ushort*)alloc(R * 64 * 2);
    ushort* xd64_b  = (ushort*)alloc(R * 64 * 2);
    ushort* dt_f    = (ushort*)alloc(R * 768 * 2);
    ushort* dt_b    = (ushort*)alloc(R * 768 * 2);
    ushort* y_f_bf  = (ushort*)alloc(R * 768 * 2);
    ushort* y_b_bf  = (ushort*)alloc(R * 768 * 2);
    float*  outraw  = (float*)alloc(R * 768 * 4);
    const size_t SCN = (size_t)4 * NCH * DINNER * 16;
    float* Hloc = (float*)alloc(SCN * 4);
    float* Wpb  = (float*)alloc(SCN * 4);
    float* Hin  = (float*)alloc(SCN * 4);
    ushort* Wt_fin = (ushort*)alloc((size_t)1536 * 384 * 2);
    ushort* Wt_bin = (ushort*)alloc((size_t)1536 * 384 * 2);
    ushort* Wt_op  = (ushort*)alloc((size_t)768 * 768 * 2);
    ushort* Wt_fxp = (ushort*)alloc((size_t)64 * 768 * 2);
    ushort* Wt_bxp = (ushort*)alloc((size_t)64 * 768 * 2);
    ushort* dtwT_f = (ushort*)alloc((size_t)768 * 64 * 2);
    ushort* dtwT_b = (ushort*)alloc((size_t)768 * 64 * 2);
    ushort* ipc    = (ushort*)alloc((size_t)768 * 768 * 2);
    ushort* fow    = (ushort*)alloc((size_t)768 * 384 * 2);
    ushort* bow    = (ushort*)alloc((size_t)768 * 384 * 2);
    ushort* WzF    = (ushort*)alloc((size_t)1536 * 768 * 2);
    ushort* WzB    = (ushort*)alloc((size_t)1536 * 768 * 2);
    ushort* WoF    = (ushort*)alloc((size_t)768 * 768 * 2);
    ushort* WoB    = (ushort*)alloc((size_t)768 * 768 * 2);
    float*  bzf    = (float*)alloc(1536 * 4);
    float*  bzb    = (float*)alloc(1536 * 4);
    float*  bo     = (float*)alloc(768 * 4);

    // ---- D1: prep (tcast + ln1) ----
    PrepArgs pa;
    int tile0 = 0, nd = 0;
    auto add = [&](const float* s, ushort* dst, int K, int N, int Kp, int Np,
                   int ldd, int mode) {
        pa.d[nd] = TD{s, dst, K, N, Kp, Np, ldd, tile0, Kp / 32, mode};
        tile0 += (Kp / 32) * (Np / 32);
        nd++;
    };
    add(f_in_w,  Wt_fin, 384, 1536, 384, 1536, 384, 0);
    add(b_in_w,  Wt_bin, 384, 1536, 384, 1536, 384, 0);
    add(op_w,    Wt_op,  768, 768,  768, 768,  768, 0);
    add(f_xp_w,  Wt_fxp, 768, 56,   768, 64,   768, 0);
    add(b_xp_w,  Wt_bxp, 768, 56,   768, 64,   768, 0);
    add(f_dt_w,  dtwT_f, 24,  768,  64,  768,  64,  0);  // zero-padded K 24->64
    add(b_dt_w,  dtwT_b, 24,  768,  64,  768,  64,  0);
    add(ip_w,    ipc,    768, 768,  768, 768,  768, 1);
    add(f_out_w, fow,    768, 384,  768, 384,  384, 1);
    add(b_out_w, bow,    768, 384,  768, 384,  384, 1);
    pa.ntc = tile0;
    for (int i = nd; i < 12; i++) pa.d[i].tile0 = 0x7fffffff;
    pa.x = x; pa.in_nw = in_nw; pa.in_nb = in_nb; pa.xn = xn_bf;
    hipLaunchKernelGGL(prep_kernel, dim3(tile0 + ROWS), dim3(256), 0, stream, pa);

    // ---- D2: weight fusion (GEMV blocks first) ----
    WfArgs wa;
    wa.fin = Wt_fin; wa.bin = Wt_bin; wa.opT = Wt_op;
    wa.ipc = ipc; wa.fow = fow; wa.bow = bow;
    wa.WzF = WzF; wa.WzB = WzB; wa.WoF = WoF; wa.WoB = WoB;
    wa.ip_b = ip_b; wa.f_in_b = f_in_b; wa.b_in_b = b_in_b;
    wa.f_out_b = f_out_b; wa.b_out_b = b_out_b; wa.op_b = op_b;
    wa.f_in_w32 = f_in_w; wa.b_in_w32 = b_in_w; wa.op_w32 = op_w;
    wa.bzf = bzf; wa.bzb = bzb; wa.bo = bo;
    hipLaunchKernelGGL(wfuse_kernel, dim3(447), dim3(256), 0, stream, wa);

    // ---- D3: xz_{f,b} = xn @ Wz + bz (K=768, ip folded in) ----
    hipLaunchKernelGGL((mfma_gemm_k<128, 128, true>), dim3(12, 32, 2), dim3(256), 0, stream,
                       xn_bf, xn_bf, 768, WzF, WzB, 768, bzf, bzb,
                       (void*)xz_f_bf, (void*)xz_b_bf, 1536, 1536, 768);

    // ---- D4: conv + silu ----
    hipLaunchKernelGGL(conv_silu_kernel, dim3(ROWS * DINNER / 256, 2), dim3(256), 0, stream,
                       xz_f_bf, xz_b_bf, f_conv_w, f_conv_b, b_conv_w, b_conv_b,
                       xc_f_bf, xc_b_bf);

    // ---- D5: xd64 = xc @ xp_w (bf16 out, cols 0..23 dt-rank, 24..55 B/C) ----
    hipLaunchKernelGGL((mfma_gemm_k<64, 64, true>), dim3(1, 64, 2), dim3(256), 0, stream,
                       xc_f_bf, xc_b_bf, 768, Wt_fxp, Wt_bxp, 768,
                       (const float*)nullptr, (const float*)nullptr,
                       (void*)xd64_f, (void*)xd64_b, 64, 64, 768);

    // ---- D6: dt = softplus(xd64 @ dtwT + dt_b), K=64, bf16 out ----
    hipLaunchKernelGGL(dt_kernel, dim3(12, 32, 2), dim3(256), 0, stream,
                       xd64_f, xd64_b, dtwT_f, dtwT_b, f_dt_b, b_dt_b, dt_f, dt_b);

    // ---- D7/D8/D9: chunked selective scan ----
    hipLaunchKernelGGL((scan_chunk_kernel<false>), dim3(DINNER / 256, NCH, 4), dim3(256), 0, stream,
                       dt_f, xc_f_bf, xd64_f, xz_f_bf, f_A_log, f_D,
                       dt_b, xc_b_bf, xd64_b, xz_b_bf, b_A_log, b_D,
                       Hloc, Wpb, (const float*)nullptr, (ushort*)nullptr, (ushort*)nullptr);
    hipLaunchKernelGGL(scan_combine, dim3(4 * DINNER * 16 / 256), dim3(256), 0, stream,
                       Hloc, Wpb, Hin);
    hipLaunchKernelGGL((scan_chunk_kernel<true>), dim3(DINNER / 256, NCH, 4), dim3(256), 0, stream,
                       dt_f, xc_f_bf, xd64_f, xz_f_bf, f_A_log, f_D,
                       dt_b, xc_b_bf, xd64_b, xz_b_bf, b_A_log, b_D,
                       (float*)nullptr, (float*)nullptr, Hin, y_f_bf, y_b_bf);

    // ---- D10: outraw = y_f @ WoF + y_b @ WoB + bo ----
    hipLaunchKernelGGL((outop_kernel<128, 64>), dim3(12, 32), dim3(256), 0, stream,
                       y_f_bf, WoF, y_b_bf, WoB, bo, outraw, 768, 768, 768, 768, 768);

    // ---- D11: final layernorm(residual + out) ----
    hipLaunchKernelGGL(ln2_kernel, dim3(ROWS), dim3(256), 0, stream,
                       x, outraw, norm_w, norm_b, (float*)d_out);
}